// Round 1
// baseline (327.620 us; speedup 1.0000x reference)
//
#include <hip/hip_runtime.h>

#define C_DIM 512
#define N_PIX 2304   // 48*48
#define B_DIM 16

typedef float floatx4 __attribute__((ext_vector_type(4)));
typedef __bf16 bf16x8 __attribute__((ext_vector_type(8)));

// fp32 -> bf16 round-to-nearest-even (values are finite; no NaN handling needed)
static __device__ __forceinline__ unsigned short f2bf(float f) {
    unsigned u = __float_as_uint(f);
    unsigned r = (u + 0x7fffu + ((u >> 16) & 1u)) >> 16;
    return (unsigned short)r;
}

// ---------------------------------------------------------------------------
// Kernel A: per-pixel attention (softplus of 1x1 conv) and 1/L2-norm over c.
// Block = 256 threads = 64 pixels x 4 c-chunks of 128. Grid = 36864/64 = 576.
// ---------------------------------------------------------------------------
__global__ __launch_bounds__(256) void prep_kernel(const float* __restrict__ x,
                                                   const float* __restrict__ w,
                                                   float* __restrict__ rnorm,
                                                   float* __restrict__ att) {
    const int tid = threadIdx.x;
    const int px = tid & 63;
    const int cc = tid >> 6;            // 0..3 (== wave id, so loop bounds are wave-uniform)
    const int pglob = blockIdx.x * 64 + px;   // blocks never straddle batches (2304 % 64 == 0)
    const int b = pglob / N_PIX;
    const int p = pglob - b * N_PIX;

    const float* xb = x + (size_t)b * C_DIM * N_PIX + p;
    float dot = 0.f, sq = 0.f;
    #pragma unroll 4
    for (int c = cc * 128; c < cc * 128 + 128; ++c) {
        float v = xb[(size_t)c * N_PIX];
        dot = fmaf(v, w[c], dot);
        sq  = fmaf(v, v, sq);
    }
    __shared__ float sdot[4][64];
    __shared__ float ssq[4][64];
    sdot[cc][px] = dot;
    ssq[cc][px]  = sq;
    __syncthreads();
    if (cc == 0) {
        dot = sdot[0][px] + sdot[1][px] + sdot[2][px] + sdot[3][px];
        sq  = ssq[0][px]  + ssq[1][px]  + ssq[2][px]  + ssq[3][px];
        // stable softplus
        float z = dot;
        float sp = (z > 0.f) ? (z + log1pf(expf(-z))) : log1pf(expf(z));
        att[pglob] = sp;
        rnorm[pglob] = 1.0f / fmaxf(sqrtf(sq), 1e-12f);
    }
}

// ---------------------------------------------------------------------------
// Kernel B: refine[b,n] += sum_m relu(f_n . f_m)^2 * att[m]
// Per-batch S = F^T F, F = x * rnorm (bf16), 128x128 tile, K=512 in KB=32.
// LDS layout [kb][n][8] (8 k-contiguous bf16 per lane) -> ds_read_b128 frags.
// MFMA 16x16x32 bf16. Epilogue: relu^2 * att, lane-group reduce, atomicAdd.
// Grid = (18, 18, 16), block = 256 (4 waves in 2x2).
// ---------------------------------------------------------------------------
__global__ __launch_bounds__(256) void refine_kernel(const float* __restrict__ x,
                                                     const float* __restrict__ rnorm,
                                                     const float* __restrict__ att,
                                                     float* __restrict__ refine) {
    const int b  = blockIdx.z;
    const int n0 = blockIdx.x * 128;
    const int m0 = blockIdx.y * 128;
    const float* xb = x + (size_t)b * C_DIM * N_PIX;
    const float* rn = rnorm + b * N_PIX;
    const float* ab = att + b * N_PIX;

    __shared__ __align__(16) unsigned short As[4 * 128 * 8];  // [kb][n][8]
    __shared__ __align__(16) unsigned short Bs[4 * 128 * 8];  // [kb][m][8]

    const int tid  = threadIdx.x;
    const int nl   = tid & 127;   // staging row within tile
    const int half = tid >> 7;    // staging k-half (k 0..15 / 16..31)
    const int lane = tid & 63;
    const int wave = tid >> 6;
    const int wr = wave >> 1, wc = wave & 1;   // 2x2 wave grid, 64x64 per wave
    const int quad = lane >> 4, lcol = lane & 15;

    const float rA = rn[n0 + nl];
    const float rB = rn[m0 + nl];

    floatx4 acc[4][4];
    #pragma unroll
    for (int i = 0; i < 4; ++i)
        #pragma unroll
        for (int j = 0; j < 4; ++j)
            acc[i][j] = (floatx4)0.f;

    for (int k0 = 0; k0 < C_DIM; k0 += 32) {
        // ---- stage: 16 k-values for one n-row (A) and one m-row (B) per thread
        const float* xa = xb + (size_t)(k0 + half * 16) * N_PIX;
        union { unsigned short u[16]; int4 v[2]; } ta, tb;
        #pragma unroll
        for (int j = 0; j < 16; ++j) {
            float va = xa[(size_t)j * N_PIX + n0 + nl];
            float vb = xa[(size_t)j * N_PIX + m0 + nl];
            ta.u[j] = f2bf(va * rA);
            tb.u[j] = f2bf(vb * rB);
        }
        __syncthreads();  // previous iteration's fragment reads complete
        *(int4*)&As[((half * 2 + 0) * 128 + nl) * 8] = ta.v[0];
        *(int4*)&As[((half * 2 + 1) * 128 + nl) * 8] = ta.v[1];
        *(int4*)&Bs[((half * 2 + 0) * 128 + nl) * 8] = tb.v[0];
        *(int4*)&Bs[((half * 2 + 1) * 128 + nl) * 8] = tb.v[1];
        __syncthreads();

        // ---- compute: 16 MFMA per wave per chunk
        bf16x8 af[4], bfr[4];
        #pragma unroll
        for (int mi = 0; mi < 4; ++mi)
            af[mi] = *(const bf16x8*)&As[(quad * 128 + wr * 64 + mi * 16 + lcol) * 8];
        #pragma unroll
        for (int ni = 0; ni < 4; ++ni)
            bfr[ni] = *(const bf16x8*)&Bs[(quad * 128 + wc * 64 + ni * 16 + lcol) * 8];
        #pragma unroll
        for (int mi = 0; mi < 4; ++mi)
            #pragma unroll
            for (int ni = 0; ni < 4; ++ni)
                acc[mi][ni] = __builtin_amdgcn_mfma_f32_16x16x32_bf16(af[mi], bfr[ni], acc[mi][ni], 0, 0, 0);
    }

    // ---- epilogue: score = relu(sim)^2; partial refine rows; reduce over cols
    float attv[4];
    #pragma unroll
    for (int ni = 0; ni < 4; ++ni)
        attv[ni] = ab[m0 + wc * 64 + ni * 16 + lcol];

    #pragma unroll
    for (int mi = 0; mi < 4; ++mi) {
        float part[4] = {0.f, 0.f, 0.f, 0.f};
        #pragma unroll
        for (int ni = 0; ni < 4; ++ni) {
            #pragma unroll
            for (int r = 0; r < 4; ++r) {
                float s = fmaxf(acc[mi][ni][r], 0.f);
                part[r] = fmaf(s * s, attv[ni], part[r]);
            }
        }
        #pragma unroll
        for (int r = 0; r < 4; ++r) {
            float v = part[r];
            v += __shfl_xor(v, 1);
            v += __shfl_xor(v, 2);
            v += __shfl_xor(v, 4);
            v += __shfl_xor(v, 8);
            if (lcol == 0) {
                atomicAdd(&refine[b * N_PIX + n0 + wr * 64 + mi * 16 + quad * 4 + r], v);
            }
        }
    }
}

// ---------------------------------------------------------------------------
// Kernel C: out[b,c] = mean_p x[b,c,p] * refine[b,p].  One wave per (b,c).
// ---------------------------------------------------------------------------
__global__ __launch_bounds__(256) void pool_kernel(const float* __restrict__ x,
                                                   const float* __restrict__ refine,
                                                   float* __restrict__ out) {
    const int tid  = threadIdx.x;
    const int lane = tid & 63;
    const int wave = tid >> 6;
    const int g = blockIdx.x * 4 + wave;   // (b*512 + c)
    const int b = g >> 9;
    const float4* xr = (const float4*)(x + (size_t)g * N_PIX);
    const float4* rr = (const float4*)(refine + (size_t)b * N_PIX);
    float s = 0.f;
    #pragma unroll
    for (int j = 0; j < 9; ++j) {          // 2304/4 = 576 float4 = 9 * 64 lanes
        float4 xv = xr[j * 64 + lane];
        float4 rv = rr[j * 64 + lane];
        s += xv.x * rv.x + xv.y * rv.y + xv.z * rv.z + xv.w * rv.w;
    }
    #pragma unroll
    for (int off = 32; off > 0; off >>= 1) s += __shfl_down(s, off);
    if (lane == 0) out[g] = s * (1.0f / N_PIX);
}

extern "C" void kernel_launch(void* const* d_in, const int* in_sizes, int n_in,
                              void* d_out, int out_size, void* d_ws, size_t ws_size,
                              hipStream_t stream) {
    const float* x = (const float*)d_in[0];
    const float* w = (const float*)d_in[1];
    float* rnorm  = (float*)d_ws;
    float* att    = rnorm + B_DIM * N_PIX;
    float* refine = att + B_DIM * N_PIX;
    float* out    = (float*)d_out;

    hipMemsetAsync(refine, 0, B_DIM * N_PIX * sizeof(float), stream);
    prep_kernel<<<dim3(B_DIM * N_PIX / 64), 256, 0, stream>>>(x, w, rnorm, att);
    refine_kernel<<<dim3(18, 18, B_DIM), 256, 0, stream>>>(x, rnorm, att, refine);
    pool_kernel<<<dim3(B_DIM * C_DIM / 4), 256, 0, stream>>>(x, refine, out);
}

// Round 2
// 253.595 us; speedup vs baseline: 1.2919x; 1.2919x over previous
//
#include <hip/hip_runtime.h>

#define C_DIM 512
#define N_PIX 2304   // 48*48
#define B_DIM 16
#define K8    (C_DIM / 8)          // 64 groups of 8 k
#define K8_STRIDE (N_PIX * 8)      // ushorts per k8 row  (18432)
#define FB_STRIDE ((size_t)K8 * K8_STRIDE)  // ushorts per batch (1179648)

typedef float floatx4 __attribute__((ext_vector_type(4)));
typedef __bf16 bf16x8 __attribute__((ext_vector_type(8)));

// fp32 -> bf16 round-to-nearest-even
static __device__ __forceinline__ unsigned short f2bf(float f) {
    unsigned u = __float_as_uint(f);
    return (unsigned short)((u + 0x7fffu + ((u >> 16) & 1u)) >> 16);
}

// async global->LDS, 16 B per lane; LDS dest = wave-uniform base + lane*16
static __device__ __forceinline__ void load_lds16(const void* g, void* l) {
    __builtin_amdgcn_global_load_lds(
        (const __attribute__((address_space(1))) unsigned int*)g,
        (__attribute__((address_space(3))) unsigned int*)l, 16, 0, 0);
}

// ---------------------------------------------------------------------------
// Kernel A: per-pixel attention (softplus of 1x1 conv) and 1/L2-norm over c.
// ---------------------------------------------------------------------------
__global__ __launch_bounds__(256) void prep_kernel(const float* __restrict__ x,
                                                   const float* __restrict__ w,
                                                   float* __restrict__ rnorm,
                                                   float* __restrict__ att) {
    const int tid = threadIdx.x;
    const int px = tid & 63;
    const int cc = tid >> 6;
    const int pglob = blockIdx.x * 64 + px;
    const int b = pglob / N_PIX;
    const int p = pglob - b * N_PIX;

    const float* xb = x + (size_t)b * C_DIM * N_PIX + p;
    float dot = 0.f, sq = 0.f;
    #pragma unroll 4
    for (int c = cc * 128; c < cc * 128 + 128; ++c) {
        float v = xb[(size_t)c * N_PIX];
        dot = fmaf(v, w[c], dot);
        sq  = fmaf(v, v, sq);
    }
    __shared__ float sdot[4][64];
    __shared__ float ssq[4][64];
    sdot[cc][px] = dot;
    ssq[cc][px]  = sq;
    __syncthreads();
    if (cc == 0) {
        dot = sdot[0][px] + sdot[1][px] + sdot[2][px] + sdot[3][px];
        sq  = ssq[0][px]  + ssq[1][px]  + ssq[2][px]  + ssq[3][px];
        float z = dot;
        float sp = (z > 0.f) ? (z + log1pf(expf(-z))) : log1pf(expf(z));
        att[pglob] = sp;
        rnorm[pglob] = 1.0f / fmaxf(sqrtf(sq), 1e-12f);
    }
}

// ---------------------------------------------------------------------------
// Kernel A2: F[b][k/8][n][k%8] = bf16(x[b,k,n] * rnorm[b,n])  (tiled for MFMA)
// Thread: one (k8, n4) -> 8 float4 coalesced reads, 64 B coalesced write.
// Grid = (36864/256, B) = (144, 16).
// ---------------------------------------------------------------------------
__global__ __launch_bounds__(256) void convert_kernel(const float* __restrict__ x,
                                                      const float* __restrict__ rnorm,
                                                      unsigned short* __restrict__ F) {
    const int b = blockIdx.y;
    const int t = blockIdx.x * 256 + threadIdx.x;     // 0..36863
    const int k8 = t / 576;                           // 576 n4-groups per k8
    const int n4 = (t - k8 * 576) * 4;
    const float* xb = x + (size_t)b * C_DIM * N_PIX;
    const float4 rv = *(const float4*)(rnorm + b * N_PIX + n4);
    union { unsigned short u[4][8]; int4 v[4]; } cell;
    #pragma unroll
    for (int kk = 0; kk < 8; ++kk) {
        float4 xv = *(const float4*)(xb + (size_t)(k8 * 8 + kk) * N_PIX + n4);
        cell.u[0][kk] = f2bf(xv.x * rv.x);
        cell.u[1][kk] = f2bf(xv.y * rv.y);
        cell.u[2][kk] = f2bf(xv.z * rv.z);
        cell.u[3][kk] = f2bf(xv.w * rv.w);
    }
    unsigned short* dst = F + (size_t)b * FB_STRIDE + (size_t)k8 * K8_STRIDE + (size_t)n4 * 8;
    #pragma unroll
    for (int i = 0; i < 4; ++i)
        *(int4*)(dst + i * 8) = cell.v[i];
}

// ---------------------------------------------------------------------------
// Kernel B: refine[b,n] += sum_m relu(f_n . f_m)^2 * att[m]
// F pre-converted bf16 in tiled layout; staging = 4x global_load_lds dwordx4
// per thread per 32-k chunk. 128x128 tile, MFMA 16x16x32, 2x2 wave grid.
// ---------------------------------------------------------------------------
__global__ __launch_bounds__(256) void refine_kernel(const unsigned short* __restrict__ F,
                                                     const float* __restrict__ att,
                                                     float* __restrict__ refine) {
    const int b  = blockIdx.z;
    const int n0 = blockIdx.x * 128;
    const int m0 = blockIdx.y * 128;
    const unsigned short* Fb = F + (size_t)b * FB_STRIDE;
    const float* ab = att + b * N_PIX;

    __shared__ __align__(16) unsigned short As[4 * 128 * 8];  // [kb][row][8]
    __shared__ __align__(16) unsigned short Bs[4 * 128 * 8];

    const int tid  = threadIdx.x;
    const int lane = tid & 63;
    const int wave = tid >> 6;
    const int wr = wave >> 1, wc = wave & 1;
    const int quad = lane >> 4, lcol = lane & 15;

    floatx4 acc[4][4];
    #pragma unroll
    for (int i = 0; i < 4; ++i)
        #pragma unroll
        for (int j = 0; j < 4; ++j)
            acc[i][j] = (floatx4)0.f;

    // wave w stages k-subchunk kb=w for both A and B strips
    const unsigned short* gA = Fb + (size_t)wave * K8_STRIDE + (size_t)n0 * 8 + lane * 8;
    const unsigned short* gB = Fb + (size_t)wave * K8_STRIDE + (size_t)m0 * 8 + lane * 8;

    for (int ck = 0; ck < 16; ++ck) {
        const unsigned short* sA = gA + (size_t)ck * (4 * K8_STRIDE);
        const unsigned short* sB = gB + (size_t)ck * (4 * K8_STRIDE);
        __syncthreads();   // previous chunk's ds_reads complete before overwrite
        load_lds16(sA,       &As[wave * 1024]);
        load_lds16(sA + 512, &As[wave * 1024 + 512]);
        load_lds16(sB,       &Bs[wave * 1024]);
        load_lds16(sB + 512, &Bs[wave * 1024 + 512]);
        __syncthreads();   // drains vmcnt -> LDS populated

        bf16x8 af[4], bfr[4];
        #pragma unroll
        for (int mi = 0; mi < 4; ++mi)
            af[mi] = *(const bf16x8*)&As[(quad * 128 + wr * 64 + mi * 16 + lcol) * 8];
        #pragma unroll
        for (int ni = 0; ni < 4; ++ni)
            bfr[ni] = *(const bf16x8*)&Bs[(quad * 128 + wc * 64 + ni * 16 + lcol) * 8];
        #pragma unroll
        for (int mi = 0; mi < 4; ++mi)
            #pragma unroll
            for (int ni = 0; ni < 4; ++ni)
                acc[mi][ni] = __builtin_amdgcn_mfma_f32_16x16x32_bf16(af[mi], bfr[ni], acc[mi][ni], 0, 0, 0);
    }

    float attv[4];
    #pragma unroll
    for (int ni = 0; ni < 4; ++ni)
        attv[ni] = ab[m0 + wc * 64 + ni * 16 + lcol];

    #pragma unroll
    for (int mi = 0; mi < 4; ++mi) {
        float part[4] = {0.f, 0.f, 0.f, 0.f};
        #pragma unroll
        for (int ni = 0; ni < 4; ++ni) {
            #pragma unroll
            for (int r = 0; r < 4; ++r) {
                float s = fmaxf(acc[mi][ni][r], 0.f);
                part[r] = fmaf(s * s, attv[ni], part[r]);
            }
        }
        #pragma unroll
        for (int r = 0; r < 4; ++r) {
            float v = part[r];
            v += __shfl_xor(v, 1);
            v += __shfl_xor(v, 2);
            v += __shfl_xor(v, 4);
            v += __shfl_xor(v, 8);
            if (lcol == 0)
                atomicAdd(&refine[b * N_PIX + n0 + wr * 64 + mi * 16 + quad * 4 + r], v);
        }
    }
}

// ---------------------------------------------------------------------------
// Fallback refine (R1 path) if ws_size can't hold F.
// ---------------------------------------------------------------------------
__global__ __launch_bounds__(256) void refine_fallback(const float* __restrict__ x,
                                                       const float* __restrict__ rnorm,
                                                       const float* __restrict__ att,
                                                       float* __restrict__ refine) {
    const int b  = blockIdx.z;
    const int n0 = blockIdx.x * 128;
    const int m0 = blockIdx.y * 128;
    const float* xb = x + (size_t)b * C_DIM * N_PIX;
    const float* rn = rnorm + b * N_PIX;
    const float* ab = att + b * N_PIX;

    __shared__ __align__(16) unsigned short As[4 * 128 * 8];
    __shared__ __align__(16) unsigned short Bs[4 * 128 * 8];

    const int tid  = threadIdx.x;
    const int nl   = tid & 127;
    const int half = tid >> 7;
    const int lane = tid & 63;
    const int wave = tid >> 6;
    const int wr = wave >> 1, wc = wave & 1;
    const int quad = lane >> 4, lcol = lane & 15;

    const float rA = rn[n0 + nl];
    const float rB = rn[m0 + nl];

    floatx4 acc[4][4];
    #pragma unroll
    for (int i = 0; i < 4; ++i)
        #pragma unroll
        for (int j = 0; j < 4; ++j)
            acc[i][j] = (floatx4)0.f;

    for (int k0 = 0; k0 < C_DIM; k0 += 32) {
        const float* xa = xb + (size_t)(k0 + half * 16) * N_PIX;
        union { unsigned short u[16]; int4 v[2]; } ta, tb;
        #pragma unroll
        for (int j = 0; j < 16; ++j) {
            float va = xa[(size_t)j * N_PIX + n0 + nl];
            float vb = xa[(size_t)j * N_PIX + m0 + nl];
            ta.u[j] = f2bf(va * rA);
            tb.u[j] = f2bf(vb * rB);
        }
        __syncthreads();
        *(int4*)&As[((half * 2 + 0) * 128 + nl) * 8] = ta.v[0];
        *(int4*)&As[((half * 2 + 1) * 128 + nl) * 8] = ta.v[1];
        *(int4*)&Bs[((half * 2 + 0) * 128 + nl) * 8] = tb.v[0];
        *(int4*)&Bs[((half * 2 + 1) * 128 + nl) * 8] = tb.v[1];
        __syncthreads();

        bf16x8 af[4], bfr[4];
        #pragma unroll
        for (int mi = 0; mi < 4; ++mi)
            af[mi] = *(const bf16x8*)&As[(quad * 128 + wr * 64 + mi * 16 + lcol) * 8];
        #pragma unroll
        for (int ni = 0; ni < 4; ++ni)
            bfr[ni] = *(const bf16x8*)&Bs[(quad * 128 + wc * 64 + ni * 16 + lcol) * 8];
        #pragma unroll
        for (int mi = 0; mi < 4; ++mi)
            #pragma unroll
            for (int ni = 0; ni < 4; ++ni)
                acc[mi][ni] = __builtin_amdgcn_mfma_f32_16x16x32_bf16(af[mi], bfr[ni], acc[mi][ni], 0, 0, 0);
    }

    float attv[4];
    #pragma unroll
    for (int ni = 0; ni < 4; ++ni)
        attv[ni] = ab[m0 + wc * 64 + ni * 16 + lcol];

    #pragma unroll
    for (int mi = 0; mi < 4; ++mi) {
        float part[4] = {0.f, 0.f, 0.f, 0.f};
        #pragma unroll
        for (int ni = 0; ni < 4; ++ni) {
            #pragma unroll
            for (int r = 0; r < 4; ++r) {
                float s = fmaxf(acc[mi][ni][r], 0.f);
                part[r] = fmaf(s * s, attv[ni], part[r]);
            }
        }
        #pragma unroll
        for (int r = 0; r < 4; ++r) {
            float v = part[r];
            v += __shfl_xor(v, 1);
            v += __shfl_xor(v, 2);
            v += __shfl_xor(v, 4);
            v += __shfl_xor(v, 8);
            if (lcol == 0)
                atomicAdd(&refine[b * N_PIX + n0 + wr * 64 + mi * 16 + quad * 4 + r], v);
        }
    }
}

// ---------------------------------------------------------------------------
// Kernel C: out[b,c] = mean_p x[b,c,p] * refine[b,p].  One wave per (b,c).
// ---------------------------------------------------------------------------
__global__ __launch_bounds__(256) void pool_kernel(const float* __restrict__ x,
                                                   const float* __restrict__ refine,
                                                   float* __restrict__ out) {
    const int tid  = threadIdx.x;
    const int lane = tid & 63;
    const int wave = tid >> 6;
    const int g = blockIdx.x * 4 + wave;
    const int b = g >> 9;
    const float4* xr = (const float4*)(x + (size_t)g * N_PIX);
    const float4* rr = (const float4*)(refine + (size_t)b * N_PIX);
    float s = 0.f;
    #pragma unroll
    for (int j = 0; j < 9; ++j) {
        float4 xv = xr[j * 64 + lane];
        float4 rv = rr[j * 64 + lane];
        s += xv.x * rv.x + xv.y * rv.y + xv.z * rv.z + xv.w * rv.w;
    }
    #pragma unroll
    for (int off = 32; off > 0; off >>= 1) s += __shfl_down(s, off);
    if (lane == 0) out[g] = s * (1.0f / N_PIX);
}

extern "C" void kernel_launch(void* const* d_in, const int* in_sizes, int n_in,
                              void* d_out, int out_size, void* d_ws, size_t ws_size,
                              hipStream_t stream) {
    const float* x = (const float*)d_in[0];
    const float* w = (const float*)d_in[1];
    float* rnorm  = (float*)d_ws;
    float* att    = rnorm + B_DIM * N_PIX;
    float* refine = att + B_DIM * N_PIX;
    unsigned short* F = (unsigned short*)(refine + B_DIM * N_PIX);
    float* out    = (float*)d_out;

    const size_t need = (size_t)3 * B_DIM * N_PIX * 4 + (size_t)B_DIM * FB_STRIDE * 2;

    hipMemsetAsync(refine, 0, B_DIM * N_PIX * sizeof(float), stream);
    prep_kernel<<<dim3(B_DIM * N_PIX / 64), 256, 0, stream>>>(x, w, rnorm, att);
    if (ws_size >= need) {
        convert_kernel<<<dim3(144, B_DIM), 256, 0, stream>>>(x, rnorm, F);
        refine_kernel<<<dim3(18, 18, B_DIM), 256, 0, stream>>>(F, att, refine);
    } else {
        refine_fallback<<<dim3(18, 18, B_DIM), 256, 0, stream>>>(x, rnorm, att, refine);
    }
    pool_kernel<<<dim3(B_DIM * C_DIM / 4), 256, 0, stream>>>(x, refine, out);
}

// Round 3
// 212.220 us; speedup vs baseline: 1.5438x; 1.1950x over previous
//
#include <hip/hip_runtime.h>

#define C_DIM 512
#define N_PIX 2304   // 48*48
#define B_DIM 16
#define K8    (C_DIM / 8)          // 64 groups of 8 k
#define K8_STRIDE (N_PIX * 8)      // ushorts per k8 row  (18432)
#define FB_STRIDE ((size_t)K8 * K8_STRIDE)  // ushorts per batch (1179648)

typedef float floatx4 __attribute__((ext_vector_type(4)));
typedef __bf16 bf16x8 __attribute__((ext_vector_type(8)));

// fp32 -> bf16 round-to-nearest-even
static __device__ __forceinline__ unsigned short f2bf(float f) {
    unsigned u = __float_as_uint(f);
    return (unsigned short)((u + 0x7fffu + ((u >> 16) & 1u)) >> 16);
}

// async global->LDS, 16 B per lane; LDS dest = wave-uniform base + lane*16
static __device__ __forceinline__ void load_lds16(const void* g, void* l) {
    __builtin_amdgcn_global_load_lds(
        (const __attribute__((address_space(1))) unsigned int*)g,
        (__attribute__((address_space(3))) unsigned int*)l, 16, 0, 0);
}

// ---------------------------------------------------------------------------
// Kernel A: per-pixel att (softplus of 1x1 conv), L2-norm and 1/norm over c.
// ---------------------------------------------------------------------------
__global__ __launch_bounds__(256) void prep_kernel(const float* __restrict__ x,
                                                   const float* __restrict__ w,
                                                   float* __restrict__ rnorm,
                                                   float* __restrict__ normb,
                                                   float* __restrict__ att) {
    const int tid = threadIdx.x;
    const int px = tid & 63;
    const int cc = tid >> 6;
    const int pglob = blockIdx.x * 64 + px;
    const int b = pglob / N_PIX;
    const int p = pglob - b * N_PIX;

    const float* xb = x + (size_t)b * C_DIM * N_PIX + p;
    float dot = 0.f, sq = 0.f;
    #pragma unroll 4
    for (int c = cc * 128; c < cc * 128 + 128; ++c) {
        float v = xb[(size_t)c * N_PIX];
        dot = fmaf(v, w[c], dot);
        sq  = fmaf(v, v, sq);
    }
    __shared__ float sdot[4][64];
    __shared__ float ssq[4][64];
    sdot[cc][px] = dot;
    ssq[cc][px]  = sq;
    __syncthreads();
    if (cc == 0) {
        dot = sdot[0][px] + sdot[1][px] + sdot[2][px] + sdot[3][px];
        sq  = ssq[0][px]  + ssq[1][px]  + ssq[2][px]  + ssq[3][px];
        float z = dot;
        float sp = (z > 0.f) ? (z + log1pf(expf(-z))) : log1pf(expf(z));
        att[pglob] = sp;
        float nv = fmaxf(sqrtf(sq), 1e-12f);
        normb[pglob] = nv;
        rnorm[pglob] = 1.0f / nv;
    }
}

// ---------------------------------------------------------------------------
// Kernel A2: F[b][k/8][n][k%8] = bf16(x[b,k,n] * rnorm[b,n])  (tiled for MFMA)
// ---------------------------------------------------------------------------
__global__ __launch_bounds__(256) void convert_kernel(const float* __restrict__ x,
                                                      const float* __restrict__ rnorm,
                                                      unsigned short* __restrict__ F) {
    const int b = blockIdx.y;
    const int t = blockIdx.x * 256 + threadIdx.x;     // 0..36863
    const int k8 = t / 576;                           // 576 n4-groups per k8
    const int n4 = (t - k8 * 576) * 4;
    const float* xb = x + (size_t)b * C_DIM * N_PIX;
    const float4 rv = *(const float4*)(rnorm + b * N_PIX + n4);
    union { unsigned short u[4][8]; int4 v[4]; } cell;
    #pragma unroll
    for (int kk = 0; kk < 8; ++kk) {
        float4 xv = *(const float4*)(xb + (size_t)(k8 * 8 + kk) * N_PIX + n4);
        cell.u[0][kk] = f2bf(xv.x * rv.x);
        cell.u[1][kk] = f2bf(xv.y * rv.y);
        cell.u[2][kk] = f2bf(xv.z * rv.z);
        cell.u[3][kk] = f2bf(xv.w * rv.w);
    }
    unsigned short* dst = F + (size_t)b * FB_STRIDE + (size_t)k8 * K8_STRIDE + (size_t)n4 * 8;
    #pragma unroll
    for (int i = 0; i < 4; ++i)
        *(int4*)(dst + i * 8) = cell.v[i];
}

// ---------------------------------------------------------------------------
// Kernel B: symmetric-triangle refine.
// Upper-triangle tiles (bi<=bj) only: 171 tiles/batch instead of 324.
// Standard: refine[row] += sum_cols s^2 * att[col]   (lcol butterfly reduce)
// Mirror (bi!=bj): refine[col] += sum_rows s^2 * att[row] (quad butterfly)
// ---------------------------------------------------------------------------
__global__ __launch_bounds__(256) void refine_kernel(const unsigned short* __restrict__ F,
                                                     const float* __restrict__ att,
                                                     float* __restrict__ refine) {
    const int b = blockIdx.z;
    // decode triangular tile index -> (bi, bj), bi <= bj
    int t = blockIdx.x, bi = 0;
    while (t >= 18 - bi) { t -= 18 - bi; ++bi; }
    const int bj = bi + t;
    const int n0 = bi * 128;          // rows
    const int m0 = bj * 128;          // cols
    const bool mirror = (bi != bj);

    const unsigned short* Fb = F + (size_t)b * FB_STRIDE;
    const float* ab = att + b * N_PIX;

    __shared__ __align__(16) unsigned short As[4 * 128 * 8];  // [kb][row][8]
    __shared__ __align__(16) unsigned short Bs[4 * 128 * 8];

    const int tid  = threadIdx.x;
    const int lane = tid & 63;
    const int wave = tid >> 6;
    const int wr = wave >> 1, wc = wave & 1;
    const int quad = lane >> 4, lcol = lane & 15;

    floatx4 acc[4][4];
    #pragma unroll
    for (int i = 0; i < 4; ++i)
        #pragma unroll
        for (int j = 0; j < 4; ++j)
            acc[i][j] = (floatx4)0.f;

    // wave w stages k-subchunk kb=w for both A and B strips
    const unsigned short* gA = Fb + (size_t)wave * K8_STRIDE + (size_t)n0 * 8 + lane * 8;
    const unsigned short* gB = Fb + (size_t)wave * K8_STRIDE + (size_t)m0 * 8 + lane * 8;

    for (int ck = 0; ck < 16; ++ck) {
        const unsigned short* sA = gA + (size_t)ck * (4 * K8_STRIDE);
        const unsigned short* sB = gB + (size_t)ck * (4 * K8_STRIDE);
        __syncthreads();
        load_lds16(sA,       &As[wave * 1024]);
        load_lds16(sA + 512, &As[wave * 1024 + 512]);
        load_lds16(sB,       &Bs[wave * 1024]);
        load_lds16(sB + 512, &Bs[wave * 1024 + 512]);
        __syncthreads();

        bf16x8 af[4], bfr[4];
        #pragma unroll
        for (int mi = 0; mi < 4; ++mi)
            af[mi] = *(const bf16x8*)&As[(quad * 128 + wr * 64 + mi * 16 + lcol) * 8];
        #pragma unroll
        for (int ni = 0; ni < 4; ++ni)
            bfr[ni] = *(const bf16x8*)&Bs[(quad * 128 + wc * 64 + ni * 16 + lcol) * 8];
        #pragma unroll
        for (int mi = 0; mi < 4; ++mi)
            #pragma unroll
            for (int ni = 0; ni < 4; ++ni)
                acc[mi][ni] = __builtin_amdgcn_mfma_f32_16x16x32_bf16(af[mi], bfr[ni], acc[mi][ni], 0, 0, 0);
    }

    // ---- standard contribution: reduce over cols -> refine[rows]
    float attC[4];
    #pragma unroll
    for (int ni = 0; ni < 4; ++ni)
        attC[ni] = ab[m0 + wc * 64 + ni * 16 + lcol];

    #pragma unroll
    for (int mi = 0; mi < 4; ++mi) {
        float part[4] = {0.f, 0.f, 0.f, 0.f};
        #pragma unroll
        for (int ni = 0; ni < 4; ++ni) {
            #pragma unroll
            for (int r = 0; r < 4; ++r) {
                float s = fmaxf(acc[mi][ni][r], 0.f);
                part[r] = fmaf(s * s, attC[ni], part[r]);
            }
        }
        #pragma unroll
        for (int r = 0; r < 4; ++r) {
            float v = part[r];
            v += __shfl_xor(v, 1);
            v += __shfl_xor(v, 2);
            v += __shfl_xor(v, 4);
            v += __shfl_xor(v, 8);
            if (lcol == 0)
                atomicAdd(&refine[b * N_PIX + n0 + wr * 64 + mi * 16 + quad * 4 + r], v);
        }
    }

    // ---- mirror contribution: reduce over rows -> refine[cols]
    if (mirror) {
        float attR[4][4];
        #pragma unroll
        for (int mi = 0; mi < 4; ++mi)
            #pragma unroll
            for (int r = 0; r < 4; ++r)
                attR[mi][r] = ab[n0 + wr * 64 + mi * 16 + quad * 4 + r];

        #pragma unroll
        for (int ni = 0; ni < 4; ++ni) {
            float msum = 0.f;
            #pragma unroll
            for (int mi = 0; mi < 4; ++mi) {
                #pragma unroll
                for (int r = 0; r < 4; ++r) {
                    float s = fmaxf(acc[mi][ni][r], 0.f);
                    msum = fmaf(s * s, attR[mi][r], msum);
                }
            }
            msum += __shfl_xor(msum, 16);
            msum += __shfl_xor(msum, 32);
            if (quad == 0)
                atomicAdd(&refine[b * N_PIX + m0 + wc * 64 + ni * 16 + lcol], msum);
        }
    }
}

// ---------------------------------------------------------------------------
// Fallback refine (R1 path, full 18x18 grid) if ws can't hold F.
// ---------------------------------------------------------------------------
__global__ __launch_bounds__(256) void refine_fallback(const float* __restrict__ x,
                                                       const float* __restrict__ rnorm,
                                                       const float* __restrict__ att,
                                                       float* __restrict__ refine) {
    const int b  = blockIdx.z;
    const int n0 = blockIdx.x * 128;
    const int m0 = blockIdx.y * 128;
    const float* xb = x + (size_t)b * C_DIM * N_PIX;
    const float* rn = rnorm + b * N_PIX;
    const float* ab = att + b * N_PIX;

    __shared__ __align__(16) unsigned short As[4 * 128 * 8];
    __shared__ __align__(16) unsigned short Bs[4 * 128 * 8];

    const int tid  = threadIdx.x;
    const int nl   = tid & 127;
    const int half = tid >> 7;
    const int lane = tid & 63;
    const int wave = tid >> 6;
    const int wr = wave >> 1, wc = wave & 1;
    const int quad = lane >> 4, lcol = lane & 15;

    const float rA = rn[n0 + nl];
    const float rB = rn[m0 + nl];

    floatx4 acc[4][4];
    #pragma unroll
    for (int i = 0; i < 4; ++i)
        #pragma unroll
        for (int j = 0; j < 4; ++j)
            acc[i][j] = (floatx4)0.f;

    for (int k0 = 0; k0 < C_DIM; k0 += 32) {
        const float* xa = xb + (size_t)(k0 + half * 16) * N_PIX;
        union { unsigned short u[16]; int4 v[2]; } ta, tb;
        #pragma unroll
        for (int j = 0; j < 16; ++j) {
            float va = xa[(size_t)j * N_PIX + n0 + nl];
            float vb = xa[(size_t)j * N_PIX + m0 + nl];
            ta.u[j] = f2bf(va * rA);
            tb.u[j] = f2bf(vb * rB);
        }
        __syncthreads();
        *(int4*)&As[((half * 2 + 0) * 128 + nl) * 8] = ta.v[0];
        *(int4*)&As[((half * 2 + 1) * 128 + nl) * 8] = ta.v[1];
        *(int4*)&Bs[((half * 2 + 0) * 128 + nl) * 8] = tb.v[0];
        *(int4*)&Bs[((half * 2 + 1) * 128 + nl) * 8] = tb.v[1];
        __syncthreads();

        bf16x8 af[4], bfr[4];
        #pragma unroll
        for (int mi = 0; mi < 4; ++mi)
            af[mi] = *(const bf16x8*)&As[(quad * 128 + wr * 64 + mi * 16 + lcol) * 8];
        #pragma unroll
        for (int ni = 0; ni < 4; ++ni)
            bfr[ni] = *(const bf16x8*)&Bs[(quad * 128 + wc * 64 + ni * 16 + lcol) * 8];
        #pragma unroll
        for (int mi = 0; mi < 4; ++mi)
            #pragma unroll
            for (int ni = 0; ni < 4; ++ni)
                acc[mi][ni] = __builtin_amdgcn_mfma_f32_16x16x32_bf16(af[mi], bfr[ni], acc[mi][ni], 0, 0, 0);
    }

    float attv[4];
    #pragma unroll
    for (int ni = 0; ni < 4; ++ni)
        attv[ni] = ab[m0 + wc * 64 + ni * 16 + lcol];

    #pragma unroll
    for (int mi = 0; mi < 4; ++mi) {
        float part[4] = {0.f, 0.f, 0.f, 0.f};
        #pragma unroll
        for (int ni = 0; ni < 4; ++ni) {
            #pragma unroll
            for (int r = 0; r < 4; ++r) {
                float s = fmaxf(acc[mi][ni][r], 0.f);
                part[r] = fmaf(s * s, attv[ni], part[r]);
            }
        }
        #pragma unroll
        for (int r = 0; r < 4; ++r) {
            float v = part[r];
            v += __shfl_xor(v, 1);
            v += __shfl_xor(v, 2);
            v += __shfl_xor(v, 4);
            v += __shfl_xor(v, 8);
            if (lcol == 0)
                atomicAdd(&refine[b * N_PIX + n0 + wr * 64 + mi * 16 + quad * 4 + r], v);
        }
    }
}

// ---------------------------------------------------------------------------
// Kernel C: out[b,c] = mean_p F[b,c,p]*norm[p]*refine[b,p]  (F is x/norm).
// One wave per (b,k8) covering 8 channels; bf16x8 coalesced loads.
// ---------------------------------------------------------------------------
__global__ __launch_bounds__(256) void pool_kernel(const unsigned short* __restrict__ F,
                                                   const float* __restrict__ refine,
                                                   const float* __restrict__ normb,
                                                   float* __restrict__ out) {
    const int lane = threadIdx.x & 63;
    const int wave = threadIdx.x >> 6;
    const int g = blockIdx.x * 4 + wave;      // b*64 + k8
    const int b = g >> 6;
    const int k8 = g & 63;
    const unsigned short* Fr = F + (size_t)b * FB_STRIDE + (size_t)k8 * K8_STRIDE;
    const float* rf = refine + b * N_PIX;
    const float* nb = normb + b * N_PIX;
    float s[8] = {0.f, 0.f, 0.f, 0.f, 0.f, 0.f, 0.f, 0.f};
    #pragma unroll 4
    for (int j = 0; j < 36; ++j) {            // 2304 / 64
        const int n = j * 64 + lane;
        bf16x8 fv = *(const bf16x8*)(Fr + (size_t)n * 8);
        float rr = rf[n] * nb[n];
        #pragma unroll
        for (int kk = 0; kk < 8; ++kk)
            s[kk] = fmaf((float)fv[kk], rr, s[kk]);
    }
    #pragma unroll
    for (int kk = 0; kk < 8; ++kk) {
        float v = s[kk];
        #pragma unroll
        for (int off = 32; off > 0; off >>= 1) v += __shfl_down(v, off);
        if (lane == 0) out[b * C_DIM + k8 * 8 + kk] = v * (1.0f / N_PIX);
    }
}

// Fallback pool (reads fp32 x) for the no-ws path.
__global__ __launch_bounds__(256) void pool_fallback(const float* __restrict__ x,
                                                     const float* __restrict__ refine,
                                                     float* __restrict__ out) {
    const int lane = threadIdx.x & 63;
    const int wave = threadIdx.x >> 6;
    const int g = blockIdx.x * 4 + wave;
    const int b = g >> 9;
    const float4* xr = (const float4*)(x + (size_t)g * N_PIX);
    const float4* rr = (const float4*)(refine + (size_t)b * N_PIX);
    float s = 0.f;
    #pragma unroll
    for (int j = 0; j < 9; ++j) {
        float4 xv = xr[j * 64 + lane];
        float4 rv = rr[j * 64 + lane];
        s += xv.x * rv.x + xv.y * rv.y + xv.z * rv.z + xv.w * rv.w;
    }
    #pragma unroll
    for (int off = 32; off > 0; off >>= 1) s += __shfl_down(s, off);
    if (lane == 0) out[g] = s * (1.0f / N_PIX);
}

extern "C" void kernel_launch(void* const* d_in, const int* in_sizes, int n_in,
                              void* d_out, int out_size, void* d_ws, size_t ws_size,
                              hipStream_t stream) {
    const float* x = (const float*)d_in[0];
    const float* w = (const float*)d_in[1];
    float* rnorm  = (float*)d_ws;
    float* normb  = rnorm + B_DIM * N_PIX;
    float* att    = normb + B_DIM * N_PIX;
    float* refine = att + B_DIM * N_PIX;
    unsigned short* F = (unsigned short*)(refine + B_DIM * N_PIX);
    float* out    = (float*)d_out;

    const size_t need = (size_t)4 * B_DIM * N_PIX * 4 + (size_t)B_DIM * FB_STRIDE * 2;

    hipMemsetAsync(refine, 0, B_DIM * N_PIX * sizeof(float), stream);
    prep_kernel<<<dim3(B_DIM * N_PIX / 64), 256, 0, stream>>>(x, w, rnorm, normb, att);
    if (ws_size >= need) {
        convert_kernel<<<dim3(144, B_DIM), 256, 0, stream>>>(x, rnorm, F);
        refine_kernel<<<dim3(171, 1, B_DIM), 256, 0, stream>>>(F, att, refine);
        pool_kernel<<<dim3(B_DIM * K8 / 4), 256, 0, stream>>>(F, refine, normb, out);
    } else {
        refine_fallback<<<dim3(18, 18, B_DIM), 256, 0, stream>>>(x, rnorm, att, refine);
        pool_fallback<<<dim3(B_DIM * C_DIM / 4), 256, 0, stream>>>(x, refine, out);
    }
}

// Round 4
// 210.838 us; speedup vs baseline: 1.5539x; 1.0066x over previous
//
#include <hip/hip_runtime.h>

#define C_DIM 512
#define N_PIX 2304   // 48*48
#define B_DIM 16
#define K8    (C_DIM / 8)          // 64 groups of 8 k
#define K8_STRIDE (N_PIX * 8)      // ushorts per k8 row  (18432)
#define FB_STRIDE ((size_t)K8 * K8_STRIDE)  // ushorts per batch (1179648)

typedef float floatx4 __attribute__((ext_vector_type(4)));
typedef __bf16 bf16x8 __attribute__((ext_vector_type(8)));

// fp32 -> bf16 round-to-nearest-even
static __device__ __forceinline__ unsigned short f2bf(float f) {
    unsigned u = __float_as_uint(f);
    return (unsigned short)((u + 0x7fffu + ((u >> 16) & 1u)) >> 16);
}

// async global->LDS, 16 B per lane; LDS dest = wave-uniform base + lane*16
static __device__ __forceinline__ void load_lds16(const void* g, void* l) {
    __builtin_amdgcn_global_load_lds(
        (const __attribute__((address_space(1))) unsigned int*)g,
        (__attribute__((address_space(3))) unsigned int*)l, 16, 0, 0);
}

// ---------------------------------------------------------------------------
// Fused prep+convert: one block = one 64-pixel window of one batch.
// Phase 1: att (softplus), norm, 1/norm per pixel (x window -> L2).
// Phase 2: re-read window from L2, write F[b][k/8][n][k%8] = bf16(x * rnorm).
// Grid = 576, block = 256.
// ---------------------------------------------------------------------------
__global__ __launch_bounds__(256) void prep_convert_kernel(const float* __restrict__ x,
                                                           const float* __restrict__ w,
                                                           float* __restrict__ rnorm,
                                                           float* __restrict__ normb,
                                                           float* __restrict__ att,
                                                           unsigned short* __restrict__ F) {
    const int tid = threadIdx.x;
    const int px = tid & 63;
    const int cc = tid >> 6;
    const int b  = (blockIdx.x * 64) / N_PIX;     // uniform (2304 % 64 == 0)
    const int p0 = (blockIdx.x * 64) % N_PIX;     // uniform window base
    const int p  = p0 + px;

    const float* xb = x + (size_t)b * C_DIM * N_PIX;

    // ---- phase 1: dot(w,x) and sum(x^2) over c, split 4 ways
    float dot = 0.f, sq = 0.f;
    #pragma unroll 4
    for (int c = cc * 128; c < cc * 128 + 128; ++c) {
        float v = xb[(size_t)c * N_PIX + p];
        dot = fmaf(v, w[c], dot);
        sq  = fmaf(v, v, sq);
    }
    __shared__ float sdot[4][64];
    __shared__ float ssq[4][64];
    __shared__ __align__(16) float srn[64];
    sdot[cc][px] = dot;
    ssq[cc][px]  = sq;
    __syncthreads();
    if (cc == 0) {
        dot = sdot[0][px] + sdot[1][px] + sdot[2][px] + sdot[3][px];
        sq  = ssq[0][px]  + ssq[1][px]  + ssq[2][px]  + ssq[3][px];
        float z = dot;
        float sp = (z > 0.f) ? (z + log1pf(expf(-z))) : log1pf(expf(z));
        att[b * N_PIX + p] = sp;
        float nv = fmaxf(sqrtf(sq), 1e-12f);
        normb[b * N_PIX + p] = nv;
        float rv = 1.0f / nv;
        rnorm[b * N_PIX + p] = rv;
        srn[px] = rv;
    }
    __syncthreads();

    // ---- phase 2: tiled bf16 F for this window (reads are L2-hot)
    const int n4l = tid & 15;          // local group of 4 pixels
    const int k8b = tid >> 4;          // 0..15
    const float4 rv4 = *(const float4*)&srn[n4l * 4];
    #pragma unroll
    for (int it = 0; it < 4; ++it) {
        const int k8 = k8b + 16 * it;
        union { unsigned short u[4][8]; int4 v[4]; } cell;
        #pragma unroll
        for (int kk = 0; kk < 8; ++kk) {
            float4 xv = *(const float4*)(xb + (size_t)(k8 * 8 + kk) * N_PIX + p0 + n4l * 4);
            cell.u[0][kk] = f2bf(xv.x * rv4.x);
            cell.u[1][kk] = f2bf(xv.y * rv4.y);
            cell.u[2][kk] = f2bf(xv.z * rv4.z);
            cell.u[3][kk] = f2bf(xv.w * rv4.w);
        }
        unsigned short* dst = F + (size_t)b * FB_STRIDE + (size_t)k8 * K8_STRIDE
                            + (size_t)(p0 + n4l * 4) * 8;
        #pragma unroll
        for (int i = 0; i < 4; ++i)
            *(int4*)(dst + i * 8) = cell.v[i];
    }
}

// ---------------------------------------------------------------------------
// Kernel B: symmetric-triangle refine, XCD-partitioned, BK=64.
// Flat grid 2736: xcd = id&7 holds batches {xcd, xcd+8} -> F_b stays L2-hot.
// 8 barrier-pairs of 32 MFMA each (K=512, BK=64, LDS 2x16 KB).
// ---------------------------------------------------------------------------
__global__ __launch_bounds__(256) void refine_kernel(const unsigned short* __restrict__ F,
                                                     const float* __restrict__ att,
                                                     float* __restrict__ refine) {
    // ---- decode: XCD-partitioned (id%8 ~ XCD), then triangular tile
    const int id   = blockIdx.x;
    const int xcd  = id & 7;
    const int slot = id >> 3;                  // 0..341
    const int hi   = (slot >= 171) ? 1 : 0;
    const int b    = xcd + 8 * hi;
    int t = slot - 171 * hi, bi = 0;
    while (t >= 18 - bi) { t -= 18 - bi; ++bi; }
    const int bj = bi + t;
    const int n0 = bi * 128;          // rows
    const int m0 = bj * 128;          // cols
    const bool mirror = (bi != bj);

    const unsigned short* Fb = F + (size_t)b * FB_STRIDE;
    const float* ab = att + b * N_PIX;

    __shared__ __align__(16) unsigned short As[8 * 128 * 8];  // [kb][row][8]
    __shared__ __align__(16) unsigned short Bs[8 * 128 * 8];

    const int tid  = threadIdx.x;
    const int lane = tid & 63;
    const int wave = tid >> 6;
    const int wr = wave >> 1, wc = wave & 1;
    const int quad = lane >> 4, lcol = lane & 15;

    floatx4 acc[4][4];
    #pragma unroll
    for (int i = 0; i < 4; ++i)
        #pragma unroll
        for (int j = 0; j < 4; ++j)
            acc[i][j] = (floatx4)0.f;

    for (int ck = 0; ck < 8; ++ck) {
        __syncthreads();   // previous iteration's ds_reads complete
        #pragma unroll
        for (int h = 0; h < 2; ++h) {
            const int kbl = wave * 2 + h;                    // local k8 group 0..7
            const unsigned short* sA = Fb + (size_t)(ck * 8 + kbl) * K8_STRIDE
                                     + (size_t)n0 * 8 + lane * 8;
            const unsigned short* sB = Fb + (size_t)(ck * 8 + kbl) * K8_STRIDE
                                     + (size_t)m0 * 8 + lane * 8;
            load_lds16(sA,       &As[kbl * 1024]);
            load_lds16(sA + 512, &As[kbl * 1024 + 512]);
            load_lds16(sB,       &Bs[kbl * 1024]);
            load_lds16(sB + 512, &Bs[kbl * 1024 + 512]);
        }
        __syncthreads();   // drains vmcnt -> LDS populated

        #pragma unroll
        for (int h = 0; h < 2; ++h) {
            const int kb = h * 4 + quad;
            bf16x8 af[4], bfr[4];
            #pragma unroll
            for (int mi = 0; mi < 4; ++mi)
                af[mi] = *(const bf16x8*)&As[(kb * 128 + wr * 64 + mi * 16 + lcol) * 8];
            #pragma unroll
            for (int ni = 0; ni < 4; ++ni)
                bfr[ni] = *(const bf16x8*)&Bs[(kb * 128 + wc * 64 + ni * 16 + lcol) * 8];
            #pragma unroll
            for (int mi = 0; mi < 4; ++mi)
                #pragma unroll
                for (int ni = 0; ni < 4; ++ni)
                    acc[mi][ni] = __builtin_amdgcn_mfma_f32_16x16x32_bf16(af[mi], bfr[ni], acc[mi][ni], 0, 0, 0);
        }
    }

    // ---- standard contribution: reduce over cols -> refine[rows]
    float attC[4];
    #pragma unroll
    for (int ni = 0; ni < 4; ++ni)
        attC[ni] = ab[m0 + wc * 64 + ni * 16 + lcol];

    #pragma unroll
    for (int mi = 0; mi < 4; ++mi) {
        float part[4] = {0.f, 0.f, 0.f, 0.f};
        #pragma unroll
        for (int ni = 0; ni < 4; ++ni) {
            #pragma unroll
            for (int r = 0; r < 4; ++r) {
                float s = fmaxf(acc[mi][ni][r], 0.f);
                part[r] = fmaf(s * s, attC[ni], part[r]);
            }
        }
        #pragma unroll
        for (int r = 0; r < 4; ++r) {
            float v = part[r];
            v += __shfl_xor(v, 1);
            v += __shfl_xor(v, 2);
            v += __shfl_xor(v, 4);
            v += __shfl_xor(v, 8);
            if (lcol == 0)
                atomicAdd(&refine[b * N_PIX + n0 + wr * 64 + mi * 16 + quad * 4 + r], v);
        }
    }

    // ---- mirror contribution: reduce over rows -> refine[cols]
    if (mirror) {
        float attR[4][4];
        #pragma unroll
        for (int mi = 0; mi < 4; ++mi)
            #pragma unroll
            for (int r = 0; r < 4; ++r)
                attR[mi][r] = ab[n0 + wr * 64 + mi * 16 + quad * 4 + r];

        #pragma unroll
        for (int ni = 0; ni < 4; ++ni) {
            float msum = 0.f;
            #pragma unroll
            for (int mi = 0; mi < 4; ++mi) {
                #pragma unroll
                for (int r = 0; r < 4; ++r) {
                    float s = fmaxf(acc[mi][ni][r], 0.f);
                    msum = fmaf(s * s, attR[mi][r], msum);
                }
            }
            msum += __shfl_xor(msum, 16);
            msum += __shfl_xor(msum, 32);
            if (quad == 0)
                atomicAdd(&refine[b * N_PIX + m0 + wc * 64 + ni * 16 + lcol], msum);
        }
    }
}

// ---------------------------------------------------------------------------
// Fallback refine (R1 path, full 18x18 grid) if ws can't hold F.
// ---------------------------------------------------------------------------
__global__ __launch_bounds__(256) void refine_fallback(const float* __restrict__ x,
                                                       const float* __restrict__ rnorm,
                                                       const float* __restrict__ att,
                                                       float* __restrict__ refine) {
    const int b  = blockIdx.z;
    const int n0 = blockIdx.x * 128;
    const int m0 = blockIdx.y * 128;
    const float* xb = x + (size_t)b * C_DIM * N_PIX;
    const float* rn = rnorm + b * N_PIX;
    const float* ab = att + b * N_PIX;

    __shared__ __align__(16) unsigned short As[4 * 128 * 8];
    __shared__ __align__(16) unsigned short Bs[4 * 128 * 8];

    const int tid  = threadIdx.x;
    const int nl   = tid & 127;
    const int half = tid >> 7;
    const int lane = tid & 63;
    const int wave = tid >> 6;
    const int wr = wave >> 1, wc = wave & 1;
    const int quad = lane >> 4, lcol = lane & 15;

    const float rA = rn[n0 + nl];
    const float rB = rn[m0 + nl];

    floatx4 acc[4][4];
    #pragma unroll
    for (int i = 0; i < 4; ++i)
        #pragma unroll
        for (int j = 0; j < 4; ++j)
            acc[i][j] = (floatx4)0.f;

    for (int k0 = 0; k0 < C_DIM; k0 += 32) {
        const float* xa = xb + (size_t)(k0 + half * 16) * N_PIX;
        union { unsigned short u[16]; int4 v[2]; } ta, tb;
        #pragma unroll
        for (int j = 0; j < 16; ++j) {
            float va = xa[(size_t)j * N_PIX + n0 + nl];
            float vb = xa[(size_t)j * N_PIX + m0 + nl];
            ta.u[j] = f2bf(va * rA);
            tb.u[j] = f2bf(vb * rB);
        }
        __syncthreads();
        *(int4*)&As[((half * 2 + 0) * 128 + nl) * 8] = ta.v[0];
        *(int4*)&As[((half * 2 + 1) * 128 + nl) * 8] = ta.v[1];
        *(int4*)&Bs[((half * 2 + 0) * 128 + nl) * 8] = tb.v[0];
        *(int4*)&Bs[((half * 2 + 1) * 128 + nl) * 8] = tb.v[1];
        __syncthreads();

        bf16x8 af[4], bfr[4];
        #pragma unroll
        for (int mi = 0; mi < 4; ++mi)
            af[mi] = *(const bf16x8*)&As[(quad * 128 + wr * 64 + mi * 16 + lcol) * 8];
        #pragma unroll
        for (int ni = 0; ni < 4; ++ni)
            bfr[ni] = *(const bf16x8*)&Bs[(quad * 128 + wc * 64 + ni * 16 + lcol) * 8];
        #pragma unroll
        for (int mi = 0; mi < 4; ++mi)
            #pragma unroll
            for (int ni = 0; ni < 4; ++ni)
                acc[mi][ni] = __builtin_amdgcn_mfma_f32_16x16x32_bf16(af[mi], bfr[ni], acc[mi][ni], 0, 0, 0);
    }

    float attv[4];
    #pragma unroll
    for (int ni = 0; ni < 4; ++ni)
        attv[ni] = ab[m0 + wc * 64 + ni * 16 + lcol];

    #pragma unroll
    for (int mi = 0; mi < 4; ++mi) {
        float part[4] = {0.f, 0.f, 0.f, 0.f};
        #pragma unroll
        for (int ni = 0; ni < 4; ++ni) {
            #pragma unroll
            for (int r = 0; r < 4; ++r) {
                float s = fmaxf(acc[mi][ni][r], 0.f);
                part[r] = fmaf(s * s, attv[ni], part[r]);
            }
        }
        #pragma unroll
        for (int r = 0; r < 4; ++r) {
            float v = part[r];
            v += __shfl_xor(v, 1);
            v += __shfl_xor(v, 2);
            v += __shfl_xor(v, 4);
            v += __shfl_xor(v, 8);
            if (lcol == 0)
                atomicAdd(&refine[b * N_PIX + n0 + wr * 64 + mi * 16 + quad * 4 + r], v);
        }
    }
}

// ---------------------------------------------------------------------------
// Kernel C: out[b,c] = mean_p F[b,c,p]*norm[p]*refine[b,p]  (F is x/norm).
// ---------------------------------------------------------------------------
__global__ __launch_bounds__(256) void pool_kernel(const unsigned short* __restrict__ F,
                                                   const float* __restrict__ refine,
                                                   const float* __restrict__ normb,
                                                   float* __restrict__ out) {
    const int lane = threadIdx.x & 63;
    const int wave = threadIdx.x >> 6;
    const int g = blockIdx.x * 4 + wave;      // b*64 + k8
    const int b = g >> 6;
    const int k8 = g & 63;
    const unsigned short* Fr = F + (size_t)b * FB_STRIDE + (size_t)k8 * K8_STRIDE;
    const float* rf = refine + b * N_PIX;
    const float* nb = normb + b * N_PIX;
    float s[8] = {0.f, 0.f, 0.f, 0.f, 0.f, 0.f, 0.f, 0.f};
    #pragma unroll 4
    for (int j = 0; j < 36; ++j) {            // 2304 / 64
        const int n = j * 64 + lane;
        bf16x8 fv = *(const bf16x8*)(Fr + (size_t)n * 8);
        float rr = rf[n] * nb[n];
        #pragma unroll
        for (int kk = 0; kk < 8; ++kk)
            s[kk] = fmaf((float)fv[kk], rr, s[kk]);
    }
    #pragma unroll
    for (int kk = 0; kk < 8; ++kk) {
        float v = s[kk];
        #pragma unroll
        for (int off = 32; off > 0; off >>= 1) v += __shfl_down(v, off);
        if (lane == 0) out[b * C_DIM + k8 * 8 + kk] = v * (1.0f / N_PIX);
    }
}

// Fallback pool (reads fp32 x) for the no-ws path.
__global__ __launch_bounds__(256) void pool_fallback(const float* __restrict__ x,
                                                     const float* __restrict__ refine,
                                                     float* __restrict__ out) {
    const int lane = threadIdx.x & 63;
    const int wave = threadIdx.x >> 6;
    const int g = blockIdx.x * 4 + wave;
    const int b = g >> 9;
    const float4* xr = (const float4*)(x + (size_t)g * N_PIX);
    const float4* rr = (const float4*)(refine + (size_t)b * N_PIX);
    float s = 0.f;
    #pragma unroll
    for (int j = 0; j < 9; ++j) {
        float4 xv = xr[j * 64 + lane];
        float4 rv = rr[j * 64 + lane];
        s += xv.x * rv.x + xv.y * rv.y + xv.z * rv.z + xv.w * rv.w;
    }
    #pragma unroll
    for (int off = 32; off > 0; off >>= 1) s += __shfl_down(s, off);
    if (lane == 0) out[g] = s * (1.0f / N_PIX);
}

// Fallback prep (writes rnorm/normb/att only).
__global__ __launch_bounds__(256) void prep_kernel(const float* __restrict__ x,
                                                   const float* __restrict__ w,
                                                   float* __restrict__ rnorm,
                                                   float* __restrict__ normb,
                                                   float* __restrict__ att) {
    const int tid = threadIdx.x;
    const int px = tid & 63;
    const int cc = tid >> 6;
    const int pglob = blockIdx.x * 64 + px;
    const int b = pglob / N_PIX;
    const int p = pglob - b * N_PIX;

    const float* xb = x + (size_t)b * C_DIM * N_PIX + p;
    float dot = 0.f, sq = 0.f;
    #pragma unroll 4
    for (int c = cc * 128; c < cc * 128 + 128; ++c) {
        float v = xb[(size_t)c * N_PIX];
        dot = fmaf(v, w[c], dot);
        sq  = fmaf(v, v, sq);
    }
    __shared__ float sdot[4][64];
    __shared__ float ssq[4][64];
    sdot[cc][px] = dot;
    ssq[cc][px]  = sq;
    __syncthreads();
    if (cc == 0) {
        dot = sdot[0][px] + sdot[1][px] + sdot[2][px] + sdot[3][px];
        sq  = ssq[0][px]  + ssq[1][px]  + ssq[2][px]  + ssq[3][px];
        float z = dot;
        float sp = (z > 0.f) ? (z + log1pf(expf(-z))) : log1pf(expf(z));
        att[pglob] = sp;
        float nv = fmaxf(sqrtf(sq), 1e-12f);
        normb[pglob] = nv;
        rnorm[pglob] = 1.0f / nv;
    }
}

extern "C" void kernel_launch(void* const* d_in, const int* in_sizes, int n_in,
                              void* d_out, int out_size, void* d_ws, size_t ws_size,
                              hipStream_t stream) {
    const float* x = (const float*)d_in[0];
    const float* w = (const float*)d_in[1];
    float* rnorm  = (float*)d_ws;
    float* normb  = rnorm + B_DIM * N_PIX;
    float* att    = normb + B_DIM * N_PIX;
    float* refine = att + B_DIM * N_PIX;
    unsigned short* F = (unsigned short*)(refine + B_DIM * N_PIX);
    float* out    = (float*)d_out;

    const size_t need = (size_t)4 * B_DIM * N_PIX * 4 + (size_t)B_DIM * FB_STRIDE * 2;

    hipMemsetAsync(refine, 0, B_DIM * N_PIX * sizeof(float), stream);
    if (ws_size >= need) {
        prep_convert_kernel<<<dim3(B_DIM * N_PIX / 64), 256, 0, stream>>>(x, w, rnorm, normb, att, F);
        refine_kernel<<<dim3(171 * 16), 256, 0, stream>>>(F, att, refine);
        pool_kernel<<<dim3(B_DIM * K8 / 4), 256, 0, stream>>>(F, refine, normb, out);
    } else {
        prep_kernel<<<dim3(B_DIM * N_PIX / 64), 256, 0, stream>>>(x, w, rnorm, normb, att);
        refine_fallback<<<dim3(18, 18, B_DIM), 256, 0, stream>>>(x, rnorm, att, refine);
        pool_fallback<<<dim3(B_DIM * C_DIM / 4), 256, 0, stream>>>(x, refine, out);
    }
}

// Round 5
// 208.705 us; speedup vs baseline: 1.5698x; 1.0102x over previous
//
#include <hip/hip_runtime.h>

#define C_DIM 512
#define N_PIX 2304   // 48*48
#define B_DIM 16
#define K8    (C_DIM / 8)          // 64 groups of 8 k
#define K8_STRIDE (N_PIX * 8)      // ushorts per k8 row  (18432)
#define FB_STRIDE ((size_t)K8 * K8_STRIDE)  // ushorts per batch (1179648)

typedef float floatx4 __attribute__((ext_vector_type(4)));
typedef __bf16 bf16x8 __attribute__((ext_vector_type(8)));

// fp32 -> bf16 round-to-nearest-even
static __device__ __forceinline__ unsigned short f2bf(float f) {
    unsigned u = __float_as_uint(f);
    return (unsigned short)((u + 0x7fffu + ((u >> 16) & 1u)) >> 16);
}

static __device__ __forceinline__ float softplus_stable(float z) {
    return (z > 0.f) ? (z + log1pf(expf(-z))) : log1pf(expf(z));
}

// async global->LDS, 16 B per lane; LDS dest = wave-uniform base + lane*16
static __device__ __forceinline__ void load_lds16(const void* gp, void* l) {
    __builtin_amdgcn_global_load_lds(
        (const __attribute__((address_space(1))) unsigned int*)gp,
        (__attribute__((address_space(3))) unsigned int*)l, 16, 0, 0);
}

// ---------------------------------------------------------------------------
// Kernel 1 (xcvt): SINGLE pass over x.
//   - F[b][k/8][n][k%8] = bf16(x)          (RAW x — normalization folded out)
//   - g[b,n]   = softplus(dot(w,x)) * rn2   (att * 1/norm^2)
//   - rn2[b,n] = 1/max(sum x^2, 1e-24)
//   - refine[b,n] = 0                       (replaces memset launch)
// Block = 256 = 16 pixel-quads x 16 k8-groups; one 64-pixel window per block.
// ---------------------------------------------------------------------------
__global__ __launch_bounds__(256) void xcvt_kernel(const float* __restrict__ x,
                                                   const float* __restrict__ w,
                                                   float* __restrict__ g,
                                                   float* __restrict__ rn2,
                                                   float* __restrict__ refine,
                                                   unsigned short* __restrict__ F) {
    const int tid = threadIdx.x;
    const int b  = (blockIdx.x * 64) / N_PIX;     // uniform (2304 % 64 == 0)
    const int p0 = (blockIdx.x * 64) % N_PIX;
    const int n4l = tid & 15;                     // pixel quad 0..15
    const int k8b = tid >> 4;                     // 0..15

    const float* xb = x + (size_t)b * C_DIM * N_PIX;
    float4 dot4 = {0.f, 0.f, 0.f, 0.f};
    float4 sq4  = {0.f, 0.f, 0.f, 0.f};

    #pragma unroll
    for (int it = 0; it < 4; ++it) {
        const int k8 = k8b + 16 * it;
        union { unsigned short u[4][8]; int4 v[4]; } cell;
        #pragma unroll
        for (int kk = 0; kk < 8; ++kk) {
            float4 xv = *(const float4*)(xb + (size_t)(k8 * 8 + kk) * N_PIX + p0 + n4l * 4);
            const float wc = w[k8 * 8 + kk];
            dot4.x = fmaf(xv.x, wc, dot4.x);  sq4.x = fmaf(xv.x, xv.x, sq4.x);
            dot4.y = fmaf(xv.y, wc, dot4.y);  sq4.y = fmaf(xv.y, xv.y, sq4.y);
            dot4.z = fmaf(xv.z, wc, dot4.z);  sq4.z = fmaf(xv.z, xv.z, sq4.z);
            dot4.w = fmaf(xv.w, wc, dot4.w);  sq4.w = fmaf(xv.w, xv.w, sq4.w);
            cell.u[0][kk] = f2bf(xv.x);
            cell.u[1][kk] = f2bf(xv.y);
            cell.u[2][kk] = f2bf(xv.z);
            cell.u[3][kk] = f2bf(xv.w);
        }
        unsigned short* dst = F + (size_t)b * FB_STRIDE + (size_t)k8 * K8_STRIDE
                            + (size_t)(p0 + n4l * 4) * 8;
        #pragma unroll
        for (int i = 0; i < 4; ++i)
            *(int4*)(dst + i * 8) = cell.v[i];
    }

    __shared__ float4 sdot[16][16];   // [k8b][n4l]
    __shared__ float4 ssq[16][16];
    sdot[k8b][n4l] = dot4;
    ssq[k8b][n4l]  = sq4;
    __syncthreads();

    if (tid < 16) {
        float4 d = sdot[0][tid], s = ssq[0][tid];
        #pragma unroll
        for (int j = 1; j < 16; ++j) {
            float4 dj = sdot[j][tid], sj = ssq[j][tid];
            d.x += dj.x; d.y += dj.y; d.z += dj.z; d.w += dj.w;
            s.x += sj.x; s.y += sj.y; s.z += sj.z; s.w += sj.w;
        }
        float4 r2, gv;
        r2.x = 1.0f / fmaxf(s.x, 1e-24f);  gv.x = softplus_stable(d.x) * r2.x;
        r2.y = 1.0f / fmaxf(s.y, 1e-24f);  gv.y = softplus_stable(d.y) * r2.y;
        r2.z = 1.0f / fmaxf(s.z, 1e-24f);  gv.z = softplus_stable(d.z) * r2.z;
        r2.w = 1.0f / fmaxf(s.w, 1e-24f);  gv.w = softplus_stable(d.w) * r2.w;
        const int o = b * N_PIX + p0 + tid * 4;
        *(float4*)(g   + o) = gv;
        *(float4*)(rn2 + o) = r2;
        *(float4*)(refine + o) = (float4){0.f, 0.f, 0.f, 0.f};
    }
}

// ---------------------------------------------------------------------------
// Kernel 2: symmetric-triangle refine on RAW sim, XCD-partitioned, BK=64.
// refine_raw[n] += sum_m relu(x_n.x_m)^2 * g[m]   (+ mirror for off-diag).
// Incremental global pointers (no per-iter 64-bit muls).
// ---------------------------------------------------------------------------
__global__ __launch_bounds__(256) void refine_kernel(const unsigned short* __restrict__ F,
                                                     const float* __restrict__ g,
                                                     float* __restrict__ refine) {
    // decode: XCD-partitioned (id%8 ~ XCD), then triangular tile
    const int id   = blockIdx.x;
    const int xcd  = id & 7;
    const int slot = id >> 3;                  // 0..341
    const int hi   = (slot >= 171) ? 1 : 0;
    const int b    = xcd + 8 * hi;
    int t = slot - 171 * hi, bi = 0;
    while (t >= 18 - bi) { t -= 18 - bi; ++bi; }
    const int bj = bi + t;
    const int n0 = bi * 128;          // rows
    const int m0 = bj * 128;          // cols
    const bool mirror = (bi != bj);

    const unsigned short* Fb = F + (size_t)b * FB_STRIDE;
    const float* gb = g + b * N_PIX;

    __shared__ __align__(16) unsigned short As[8 * 128 * 8];  // [kb][row][8]
    __shared__ __align__(16) unsigned short Bs[8 * 128 * 8];

    const int tid  = threadIdx.x;
    const int lane = tid & 63;
    const int wave = tid >> 6;
    const int wr = wave >> 1, wc = wave & 1;
    const int quad = lane >> 4, lcol = lane & 15;

    floatx4 acc[4][4];
    #pragma unroll
    for (int i = 0; i < 4; ++i)
        #pragma unroll
        for (int j = 0; j < 4; ++j)
            acc[i][j] = (floatx4)0.f;

    // incremental staging pointers: wave w owns local k8 groups {2w, 2w+1}
    const unsigned short* pA = Fb + (size_t)(wave * 2) * K8_STRIDE + (size_t)n0 * 8 + lane * 8;
    const unsigned short* pB = Fb + (size_t)(wave * 2) * K8_STRIDE + (size_t)m0 * 8 + lane * 8;
    unsigned short* const lA0 = &As[(wave * 2) * 1024];
    unsigned short* const lA1 = &As[(wave * 2 + 1) * 1024];
    unsigned short* const lB0 = &Bs[(wave * 2) * 1024];
    unsigned short* const lB1 = &Bs[(wave * 2 + 1) * 1024];

    for (int ck = 0; ck < 8; ++ck) {
        __syncthreads();   // previous iteration's ds_reads complete
        load_lds16(pA,                    lA0);
        load_lds16(pA + 512,              lA0 + 512);
        load_lds16(pA + K8_STRIDE,        lA1);
        load_lds16(pA + K8_STRIDE + 512,  lA1 + 512);
        load_lds16(pB,                    lB0);
        load_lds16(pB + 512,              lB0 + 512);
        load_lds16(pB + K8_STRIDE,        lB1);
        load_lds16(pB + K8_STRIDE + 512,  lB1 + 512);
        pA += 8 * K8_STRIDE;
        pB += 8 * K8_STRIDE;
        __syncthreads();   // drains vmcnt -> LDS populated

        #pragma unroll
        for (int h = 0; h < 2; ++h) {
            const int kb = h * 4 + quad;
            bf16x8 af[4], bfr[4];
            #pragma unroll
            for (int mi = 0; mi < 4; ++mi)
                af[mi] = *(const bf16x8*)&As[(kb * 128 + wr * 64 + mi * 16 + lcol) * 8];
            #pragma unroll
            for (int ni = 0; ni < 4; ++ni)
                bfr[ni] = *(const bf16x8*)&Bs[(kb * 128 + wc * 64 + ni * 16 + lcol) * 8];
            #pragma unroll
            for (int mi = 0; mi < 4; ++mi)
                #pragma unroll
                for (int ni = 0; ni < 4; ++ni)
                    acc[mi][ni] = __builtin_amdgcn_mfma_f32_16x16x32_bf16(af[mi], bfr[ni], acc[mi][ni], 0, 0, 0);
        }
    }

    // ---- standard contribution: reduce over cols -> refine_raw[rows]
    float gC[4];
    #pragma unroll
    for (int ni = 0; ni < 4; ++ni)
        gC[ni] = gb[m0 + wc * 64 + ni * 16 + lcol];

    #pragma unroll
    for (int mi = 0; mi < 4; ++mi) {
        float part[4] = {0.f, 0.f, 0.f, 0.f};
        #pragma unroll
        for (int ni = 0; ni < 4; ++ni) {
            #pragma unroll
            for (int r = 0; r < 4; ++r) {
                float s = fmaxf(acc[mi][ni][r], 0.f);
                part[r] = fmaf(s * s, gC[ni], part[r]);
            }
        }
        #pragma unroll
        for (int r = 0; r < 4; ++r) {
            float v = part[r];
            v += __shfl_xor(v, 1);
            v += __shfl_xor(v, 2);
            v += __shfl_xor(v, 4);
            v += __shfl_xor(v, 8);
            if (lcol == 0)
                atomicAdd(&refine[b * N_PIX + n0 + wr * 64 + mi * 16 + quad * 4 + r], v);
        }
    }

    // ---- mirror contribution: reduce over rows -> refine_raw[cols]
    if (mirror) {
        float gR[4][4];
        #pragma unroll
        for (int mi = 0; mi < 4; ++mi)
            #pragma unroll
            for (int r = 0; r < 4; ++r)
                gR[mi][r] = gb[n0 + wr * 64 + mi * 16 + quad * 4 + r];

        #pragma unroll
        for (int ni = 0; ni < 4; ++ni) {
            float msum = 0.f;
            #pragma unroll
            for (int mi = 0; mi < 4; ++mi) {
                #pragma unroll
                for (int r = 0; r < 4; ++r) {
                    float s = fmaxf(acc[mi][ni][r], 0.f);
                    msum = fmaf(s * s, gR[mi][r], msum);
                }
            }
            msum += __shfl_xor(msum, 16);
            msum += __shfl_xor(msum, 32);
            if (quad == 0)
                atomicAdd(&refine[b * N_PIX + m0 + wc * 64 + ni * 16 + lcol], msum);
        }
    }
}

// ---------------------------------------------------------------------------
// Kernel 3 (pool): out[b,c] = mean_n F[b,c,n] * refine_raw[n] * rn2[n]
// (F is raw x, refine_true = refine_raw*rn2). One block per (b,k8): grid 1024,
// 4 waves split the 36 n-strips; LDS combine.
// ---------------------------------------------------------------------------
__global__ __launch_bounds__(256) void pool_kernel(const unsigned short* __restrict__ F,
                                                   const float* __restrict__ refine,
                                                   const float* __restrict__ rn2,
                                                   float* __restrict__ out) {
    const int lane = threadIdx.x & 63;
    const int wave = threadIdx.x >> 6;
    const int b  = blockIdx.x >> 6;
    const int k8 = blockIdx.x & 63;
    const unsigned short* Fr = F + (size_t)b * FB_STRIDE + (size_t)k8 * K8_STRIDE;
    const float* rf = refine + b * N_PIX;
    const float* r2 = rn2 + b * N_PIX;
    float s[8] = {0.f, 0.f, 0.f, 0.f, 0.f, 0.f, 0.f, 0.f};
    #pragma unroll
    for (int j = 0; j < 9; ++j) {             // (j*4+wave) in 0..35
        const int n = (j * 4 + wave) * 64 + lane;
        bf16x8 fv = *(const bf16x8*)(Fr + (size_t)n * 8);
        float rr = rf[n] * r2[n];
        #pragma unroll
        for (int kk = 0; kk < 8; ++kk)
            s[kk] = fmaf((float)fv[kk], rr, s[kk]);
    }
    __shared__ float sred[4][8];
    #pragma unroll
    for (int kk = 0; kk < 8; ++kk) {
        float v = s[kk];
        #pragma unroll
        for (int off = 32; off > 0; off >>= 1) v += __shfl_down(v, off);
        if (lane == 0) sred[wave][kk] = v;
    }
    __syncthreads();
    if (threadIdx.x < 8) {
        const int kk = threadIdx.x;
        out[b * C_DIM + k8 * 8 + kk] =
            (sred[0][kk] + sred[1][kk] + sred[2][kk] + sred[3][kk]) * (1.0f / N_PIX);
    }
}

// ---------------------------------------------------------------------------
// Fallback path (ws too small): R1-style, no F materialization.
// ---------------------------------------------------------------------------
__global__ __launch_bounds__(256) void prep_kernel(const float* __restrict__ x,
                                                   const float* __restrict__ w,
                                                   float* __restrict__ rnorm,
                                                   float* __restrict__ att) {
    const int tid = threadIdx.x;
    const int px = tid & 63;
    const int cc = tid >> 6;
    const int pglob = blockIdx.x * 64 + px;
    const int b = pglob / N_PIX;
    const int p = pglob - b * N_PIX;

    const float* xb = x + (size_t)b * C_DIM * N_PIX + p;
    float dot = 0.f, sq = 0.f;
    #pragma unroll 4
    for (int c = cc * 128; c < cc * 128 + 128; ++c) {
        float v = xb[(size_t)c * N_PIX];
        dot = fmaf(v, w[c], dot);
        sq  = fmaf(v, v, sq);
    }
    __shared__ float sdot[4][64];
    __shared__ float ssq[4][64];
    sdot[cc][px] = dot;
    ssq[cc][px]  = sq;
    __syncthreads();
    if (cc == 0) {
        dot = sdot[0][px] + sdot[1][px] + sdot[2][px] + sdot[3][px];
        sq  = ssq[0][px]  + ssq[1][px]  + ssq[2][px]  + ssq[3][px];
        att[pglob] = softplus_stable(dot);
        rnorm[pglob] = 1.0f / fmaxf(sqrtf(sq), 1e-12f);
    }
}

__global__ __launch_bounds__(256) void refine_fallback(const float* __restrict__ x,
                                                       const float* __restrict__ rnorm,
                                                       const float* __restrict__ att,
                                                       float* __restrict__ refine) {
    const int b  = blockIdx.z;
    const int n0 = blockIdx.x * 128;
    const int m0 = blockIdx.y * 128;
    const float* xb = x + (size_t)b * C_DIM * N_PIX;
    const float* rn = rnorm + b * N_PIX;
    const float* ab = att + b * N_PIX;

    __shared__ __align__(16) unsigned short As[4 * 128 * 8];
    __shared__ __align__(16) unsigned short Bs[4 * 128 * 8];

    const int tid  = threadIdx.x;
    const int nl   = tid & 127;
    const int half = tid >> 7;
    const int lane = tid & 63;
    const int wave = tid >> 6;
    const int wr = wave >> 1, wc = wave & 1;
    const int quad = lane >> 4, lcol = lane & 15;

    const float rA = rn[n0 + nl];
    const float rB = rn[m0 + nl];

    floatx4 acc[4][4];
    #pragma unroll
    for (int i = 0; i < 4; ++i)
        #pragma unroll
        for (int j = 0; j < 4; ++j)
            acc[i][j] = (floatx4)0.f;

    for (int k0 = 0; k0 < C_DIM; k0 += 32) {
        const float* xa = xb + (size_t)(k0 + half * 16) * N_PIX;
        union { unsigned short u[16]; int4 v[2]; } ta, tb;
        #pragma unroll
        for (int j = 0; j < 16; ++j) {
            float va = xa[(size_t)j * N_PIX + n0 + nl];
            float vb = xa[(size_t)j * N_PIX + m0 + nl];
            ta.u[j] = f2bf(va * rA);
            tb.u[j] = f2bf(vb * rB);
        }
        __syncthreads();
        *(int4*)&As[((half * 2 + 0) * 128 + nl) * 8] = ta.v[0];
        *(int4*)&As[((half * 2 + 1) * 128 + nl) * 8] = ta.v[1];
        *(int4*)&Bs[((half * 2 + 0) * 128 + nl) * 8] = tb.v[0];
        *(int4*)&Bs[((half * 2 + 1) * 128 + nl) * 8] = tb.v[1];
        __syncthreads();

        bf16x8 af[4], bfr[4];
        #pragma unroll
        for (int mi = 0; mi < 4; ++mi)
            af[mi] = *(const bf16x8*)&As[(quad * 128 + wr * 64 + mi * 16 + lcol) * 8];
        #pragma unroll
        for (int ni = 0; ni < 4; ++ni)
            bfr[ni] = *(const bf16x8*)&Bs[(quad * 128 + wc * 64 + ni * 16 + lcol) * 8];
        #pragma unroll
        for (int mi = 0; mi < 4; ++mi)
            #pragma unroll
            for (int ni = 0; ni < 4; ++ni)
                acc[mi][ni] = __builtin_amdgcn_mfma_f32_16x16x32_bf16(af[mi], bfr[ni], acc[mi][ni], 0, 0, 0);
    }

    float attv[4];
    #pragma unroll
    for (int ni = 0; ni < 4; ++ni)
        attv[ni] = ab[m0 + wc * 64 + ni * 16 + lcol];

    #pragma unroll
    for (int mi = 0; mi < 4; ++mi) {
        float part[4] = {0.f, 0.f, 0.f, 0.f};
        #pragma unroll
        for (int ni = 0; ni < 4; ++ni) {
            #pragma unroll
            for (int r = 0; r < 4; ++r) {
                float s = fmaxf(acc[mi][ni][r], 0.f);
                part[r] = fmaf(s * s, attv[ni], part[r]);
            }
        }
        #pragma unroll
        for (int r = 0; r < 4; ++r) {
            float v = part[r];
            v += __shfl_xor(v, 1);
            v += __shfl_xor(v, 2);
            v += __shfl_xor(v, 4);
            v += __shfl_xor(v, 8);
            if (lcol == 0)
                atomicAdd(&refine[b * N_PIX + n0 + wr * 64 + mi * 16 + quad * 4 + r], v);
        }
    }
}

__global__ __launch_bounds__(256) void pool_fallback(const float* __restrict__ x,
                                                     const float* __restrict__ refine,
                                                     float* __restrict__ out) {
    const int lane = threadIdx.x & 63;
    const int wave = threadIdx.x >> 6;
    const int gidx = blockIdx.x * 4 + wave;
    const int b = gidx >> 9;
    const float4* xr = (const float4*)(x + (size_t)gidx * N_PIX);
    const float4* rr = (const float4*)(refine + (size_t)b * N_PIX);
    float s = 0.f;
    #pragma unroll
    for (int j = 0; j < 9; ++j) {
        float4 xv = xr[j * 64 + lane];
        float4 rv = rr[j * 64 + lane];
        s += xv.x * rv.x + xv.y * rv.y + xv.z * rv.z + xv.w * rv.w;
    }
    #pragma unroll
    for (int off = 32; off > 0; off >>= 1) s += __shfl_down(s, off);
    if (lane == 0) out[gidx] = s * (1.0f / N_PIX);
}

extern "C" void kernel_launch(void* const* d_in, const int* in_sizes, int n_in,
                              void* d_out, int out_size, void* d_ws, size_t ws_size,
                              hipStream_t stream) {
    const float* x = (const float*)d_in[0];
    const float* w = (const float*)d_in[1];
    float* rn2    = (float*)d_ws;                 // fallback: rnorm
    float* g      = rn2 + B_DIM * N_PIX;          // fallback: att
    float* refine = g + B_DIM * N_PIX;
    unsigned short* F = (unsigned short*)(refine + B_DIM * N_PIX);
    float* out    = (float*)d_out;

    const size_t need = (size_t)3 * B_DIM * N_PIX * 4 + (size_t)B_DIM * FB_STRIDE * 2;

    if (ws_size >= need) {
        xcvt_kernel<<<dim3(B_DIM * N_PIX / 64), 256, 0, stream>>>(x, w, g, rn2, refine, F);
        refine_kernel<<<dim3(171 * 16), 256, 0, stream>>>(F, g, refine);
        pool_kernel<<<dim3(B_DIM * K8), 256, 0, stream>>>(F, refine, rn2, out);
    } else {
        hipMemsetAsync(refine, 0, B_DIM * N_PIX * sizeof(float), stream);
        prep_kernel<<<dim3(B_DIM * N_PIX / 64), 256, 0, stream>>>(x, w, rn2, g);
        refine_fallback<<<dim3(18, 18, B_DIM), 256, 0, stream>>>(x, rn2, g, refine);
        pool_fallback<<<dim3(B_DIM * C_DIM / 4), 256, 0, stream>>>(x, refine, out);
    }
}

// Round 6
// 183.550 us; speedup vs baseline: 1.7849x; 1.1371x over previous
//
#include <hip/hip_runtime.h>

#define C_DIM 512
#define N_PIX 2304   // 48*48
#define B_DIM 16
#define K8    (C_DIM / 8)          // 64 groups of 8 k
#define K8_STRIDE (N_PIX * 8)      // ushorts per k8 row  (18432)
#define FB_STRIDE ((size_t)K8 * K8_STRIDE)  // ushorts per batch (1179648)
#define NB (B_DIM * N_PIX)         // 36864 pixels total

typedef float floatx4 __attribute__((ext_vector_type(4)));
typedef __bf16 bf16x8 __attribute__((ext_vector_type(8)));

// fp32 -> bf16 round-to-nearest-even
static __device__ __forceinline__ unsigned short f2bf(float f) {
    unsigned u = __float_as_uint(f);
    return (unsigned short)((u + 0x7fffu + ((u >> 16) & 1u)) >> 16);
}

static __device__ __forceinline__ float softplus_stable(float z) {
    return (z > 0.f) ? (z + log1pf(expf(-z))) : log1pf(expf(z));
}

// async global->LDS, 16 B per lane; LDS dest = wave-uniform base + lane*16
static __device__ __forceinline__ void load_lds16(const void* gp, void* l) {
    __builtin_amdgcn_global_load_lds(
        (const __attribute__((address_space(1))) unsigned int*)gp,
        (__attribute__((address_space(3))) unsigned int*)l, 16, 0, 0);
}

// ---------------------------------------------------------------------------
// Kernel 1 (xcvt): high-occupancy single pass over x.
// Grid (144, 16): block = 256 pixels x 32 channels (4 k8 groups).
//   - F[b][k/8][n][k%8] = bf16(raw x)
//   - accd[b,n] += partial dot(w,x); accs[b,n] += partial sum x^2 (atomics)
// 2304 blocks = 9/CU -> enough waves to hide HBM latency (R5's 576 wasn't).
// ---------------------------------------------------------------------------
__global__ __launch_bounds__(256) void xcvt_kernel(const float* __restrict__ x,
                                                   const float* __restrict__ w,
                                                   unsigned short* __restrict__ F,
                                                   float* __restrict__ accd,
                                                   float* __restrict__ accs) {
    const int pg = blockIdx.x;                 // 0..143 pixel group
    const int cg = blockIdx.y;                 // 0..15 channel group
    const int b  = pg / 9;
    const int p  = (pg - b * 9) * 256 + threadIdx.x;   // pixel within batch
    const float* xb = x + (size_t)b * C_DIM * N_PIX + p;

    float dot = 0.f, sq = 0.f;
    #pragma unroll
    for (int k8l = 0; k8l < 4; ++k8l) {
        const int k8 = cg * 4 + k8l;
        float v[8];
        #pragma unroll
        for (int kk = 0; kk < 8; ++kk)
            v[kk] = xb[(size_t)(k8 * 8 + kk) * N_PIX];
        union { unsigned short u[8]; int4 q; } cell;
        #pragma unroll
        for (int kk = 0; kk < 8; ++kk) {
            dot = fmaf(v[kk], w[k8 * 8 + kk], dot);
            sq  = fmaf(v[kk], v[kk], sq);
            cell.u[kk] = f2bf(v[kk]);
        }
        *(int4*)(F + (size_t)b * FB_STRIDE + (size_t)k8 * K8_STRIDE + (size_t)p * 8) = cell.q;
    }
    atomicAdd(&accd[b * N_PIX + p], dot);
    atomicAdd(&accs[b * N_PIX + p], sq);
}

// ---------------------------------------------------------------------------
// Kernel 1b (finalize): g = softplus(dot)/max(sq,eps), rn2 = 1/max(sq,eps),
// refine = 0.  Grid 144 x 256.
// ---------------------------------------------------------------------------
__global__ __launch_bounds__(256) void finalize_kernel(const float* __restrict__ accd,
                                                       const float* __restrict__ accs,
                                                       float* __restrict__ g,
                                                       float* __restrict__ rn2,
                                                       float* __restrict__ refine) {
    const int bp = blockIdx.x * 256 + threadIdx.x;
    const float d = accd[bp];
    const float s = accs[bp];
    const float r2 = 1.0f / fmaxf(s, 1e-24f);
    g[bp]      = softplus_stable(d) * r2;
    rn2[bp]    = r2;
    refine[bp] = 0.f;
}

// ---------------------------------------------------------------------------
// Kernel 2: symmetric-triangle refine on RAW sim, XCD-partitioned.
// R3-proven staging structure: BK=32, 16 KB LDS, wave w stages kb=w (4 loads).
// refine_raw[n] += sum_m relu(x_n.x_m)^2 * g[m]   (+ mirror for off-diag).
// ---------------------------------------------------------------------------
__global__ __launch_bounds__(256) void refine_kernel(const unsigned short* __restrict__ F,
                                                     const float* __restrict__ g,
                                                     float* __restrict__ refine) {
    // decode: XCD-partitioned (id%8 ~ XCD), then triangular tile
    const int id   = blockIdx.x;
    const int xcd  = id & 7;
    const int slot = id >> 3;                  // 0..341
    const int hi   = (slot >= 171) ? 1 : 0;
    const int b    = xcd + 8 * hi;
    int t = slot - 171 * hi, bi = 0;
    while (t >= 18 - bi) { t -= 18 - bi; ++bi; }
    const int bj = bi + t;
    const int n0 = bi * 128;          // rows
    const int m0 = bj * 128;          // cols
    const bool mirror = (bi != bj);

    const unsigned short* Fb = F + (size_t)b * FB_STRIDE;
    const float* gb = g + b * N_PIX;

    __shared__ __align__(16) unsigned short As[4 * 128 * 8];  // [kb][row][8]
    __shared__ __align__(16) unsigned short Bs[4 * 128 * 8];

    const int tid  = threadIdx.x;
    const int lane = tid & 63;
    const int wave = tid >> 6;
    const int wr = wave >> 1, wc = wave & 1;
    const int quad = lane >> 4, lcol = lane & 15;

    floatx4 acc[4][4];
    #pragma unroll
    for (int i = 0; i < 4; ++i)
        #pragma unroll
        for (int j = 0; j < 4; ++j)
            acc[i][j] = (floatx4)0.f;

    // wave w stages k-subchunk kb=w for both A and B strips (R3 structure)
    const unsigned short* gA = Fb + (size_t)wave * K8_STRIDE + (size_t)n0 * 8 + lane * 8;
    const unsigned short* gB = Fb + (size_t)wave * K8_STRIDE + (size_t)m0 * 8 + lane * 8;

    for (int ck = 0; ck < 16; ++ck) {
        const unsigned short* sA = gA + (size_t)ck * (4 * K8_STRIDE);
        const unsigned short* sB = gB + (size_t)ck * (4 * K8_STRIDE);
        __syncthreads();   // previous chunk's ds_reads complete
        load_lds16(sA,       &As[wave * 1024]);
        load_lds16(sA + 512, &As[wave * 1024 + 512]);
        load_lds16(sB,       &Bs[wave * 1024]);
        load_lds16(sB + 512, &Bs[wave * 1024 + 512]);
        __syncthreads();   // drains vmcnt -> LDS populated

        bf16x8 af[4], bfr[4];
        #pragma unroll
        for (int mi = 0; mi < 4; ++mi)
            af[mi] = *(const bf16x8*)&As[(quad * 128 + wr * 64 + mi * 16 + lcol) * 8];
        #pragma unroll
        for (int ni = 0; ni < 4; ++ni)
            bfr[ni] = *(const bf16x8*)&Bs[(quad * 128 + wc * 64 + ni * 16 + lcol) * 8];
        #pragma unroll
        for (int mi = 0; mi < 4; ++mi)
            #pragma unroll
            for (int ni = 0; ni < 4; ++ni)
                acc[mi][ni] = __builtin_amdgcn_mfma_f32_16x16x32_bf16(af[mi], bfr[ni], acc[mi][ni], 0, 0, 0);
    }

    // ---- standard contribution: reduce over cols -> refine_raw[rows]
    float gC[4];
    #pragma unroll
    for (int ni = 0; ni < 4; ++ni)
        gC[ni] = gb[m0 + wc * 64 + ni * 16 + lcol];

    #pragma unroll
    for (int mi = 0; mi < 4; ++mi) {
        float part[4] = {0.f, 0.f, 0.f, 0.f};
        #pragma unroll
        for (int ni = 0; ni < 4; ++ni) {
            #pragma unroll
            for (int r = 0; r < 4; ++r) {
                float s = fmaxf(acc[mi][ni][r], 0.f);
                part[r] = fmaf(s * s, gC[ni], part[r]);
            }
        }
        #pragma unroll
        for (int r = 0; r < 4; ++r) {
            float v = part[r];
            v += __shfl_xor(v, 1);
            v += __shfl_xor(v, 2);
            v += __shfl_xor(v, 4);
            v += __shfl_xor(v, 8);
            if (lcol == 0)
                atomicAdd(&refine[b * N_PIX + n0 + wr * 64 + mi * 16 + quad * 4 + r], v);
        }
    }

    // ---- mirror contribution: reduce over rows -> refine_raw[cols]
    if (mirror) {
        float gR[4][4];
        #pragma unroll
        for (int mi = 0; mi < 4; ++mi)
            #pragma unroll
            for (int r = 0; r < 4; ++r)
                gR[mi][r] = gb[n0 + wr * 64 + mi * 16 + quad * 4 + r];

        #pragma unroll
        for (int ni = 0; ni < 4; ++ni) {
            float msum = 0.f;
            #pragma unroll
            for (int mi = 0; mi < 4; ++mi) {
                #pragma unroll
                for (int r = 0; r < 4; ++r) {
                    float s = fmaxf(acc[mi][ni][r], 0.f);
                    msum = fmaf(s * s, gR[mi][r], msum);
                }
            }
            msum += __shfl_xor(msum, 16);
            msum += __shfl_xor(msum, 32);
            if (quad == 0)
                atomicAdd(&refine[b * N_PIX + m0 + wc * 64 + ni * 16 + lcol], msum);
        }
    }
}

// ---------------------------------------------------------------------------
// Kernel 3 (pool): out[b,c] = mean_n F[b,c,n] * refine_raw[n] * rn2[n]
// One block per (b,k8): grid 1024, 4 waves split the 36 n-strips.
// ---------------------------------------------------------------------------
__global__ __launch_bounds__(256) void pool_kernel(const unsigned short* __restrict__ F,
                                                   const float* __restrict__ refine,
                                                   const float* __restrict__ rn2,
                                                   float* __restrict__ out) {
    const int lane = threadIdx.x & 63;
    const int wave = threadIdx.x >> 6;
    const int b  = blockIdx.x >> 6;
    const int k8 = blockIdx.x & 63;
    const unsigned short* Fr = F + (size_t)b * FB_STRIDE + (size_t)k8 * K8_STRIDE;
    const float* rf = refine + b * N_PIX;
    const float* r2 = rn2 + b * N_PIX;
    float s[8] = {0.f, 0.f, 0.f, 0.f, 0.f, 0.f, 0.f, 0.f};
    #pragma unroll
    for (int j = 0; j < 9; ++j) {             // (j*4+wave) in 0..35
        const int n = (j * 4 + wave) * 64 + lane;
        bf16x8 fv = *(const bf16x8*)(Fr + (size_t)n * 8);
        float rr = rf[n] * r2[n];
        #pragma unroll
        for (int kk = 0; kk < 8; ++kk)
            s[kk] = fmaf((float)fv[kk], rr, s[kk]);
    }
    __shared__ float sred[4][8];
    #pragma unroll
    for (int kk = 0; kk < 8; ++kk) {
        float v = s[kk];
        #pragma unroll
        for (int off = 32; off > 0; off >>= 1) v += __shfl_down(v, off);
        if (lane == 0) sred[wave][kk] = v;
    }
    __syncthreads();
    if (threadIdx.x < 8) {
        const int kk = threadIdx.x;
        out[b * C_DIM + k8 * 8 + kk] =
            (sred[0][kk] + sred[1][kk] + sred[2][kk] + sred[3][kk]) * (1.0f / N_PIX);
    }
}

// ---------------------------------------------------------------------------
// Fallback path (ws too small): R1-style, no F materialization.
// ---------------------------------------------------------------------------
__global__ __launch_bounds__(256) void prep_kernel(const float* __restrict__ x,
                                                   const float* __restrict__ w,
                                                   float* __restrict__ rnorm,
                                                   float* __restrict__ att) {
    const int tid = threadIdx.x;
    const int px = tid & 63;
    const int cc = tid >> 6;
    const int pglob = blockIdx.x * 64 + px;
    const int b = pglob / N_PIX;
    const int p = pglob - b * N_PIX;

    const float* xb = x + (size_t)b * C_DIM * N_PIX + p;
    float dot = 0.f, sq = 0.f;
    #pragma unroll 4
    for (int c = cc * 128; c < cc * 128 + 128; ++c) {
        float v = xb[(size_t)c * N_PIX];
        dot = fmaf(v, w[c], dot);
        sq  = fmaf(v, v, sq);
    }
    __shared__ float sdot[4][64];
    __shared__ float ssq[4][64];
    sdot[cc][px] = dot;
    ssq[cc][px]  = sq;
    __syncthreads();
    if (cc == 0) {
        dot = sdot[0][px] + sdot[1][px] + sdot[2][px] + sdot[3][px];
        sq  = ssq[0][px]  + ssq[1][px]  + ssq[2][px]  + ssq[3][px];
        att[pglob] = softplus_stable(dot);
        rnorm[pglob] = 1.0f / fmaxf(sqrtf(sq), 1e-12f);
    }
}

__global__ __launch_bounds__(256) void refine_fallback(const float* __restrict__ x,
                                                       const float* __restrict__ rnorm,
                                                       const float* __restrict__ att,
                                                       float* __restrict__ refine) {
    const int b  = blockIdx.z;
    const int n0 = blockIdx.x * 128;
    const int m0 = blockIdx.y * 128;
    const float* xb = x + (size_t)b * C_DIM * N_PIX;
    const float* rn = rnorm + b * N_PIX;
    const float* ab = att + b * N_PIX;

    __shared__ __align__(16) unsigned short As[4 * 128 * 8];
    __shared__ __align__(16) unsigned short Bs[4 * 128 * 8];

    const int tid  = threadIdx.x;
    const int nl   = tid & 127;
    const int half = tid >> 7;
    const int lane = tid & 63;
    const int wave = tid >> 6;
    const int wr = wave >> 1, wc = wave & 1;
    const int quad = lane >> 4, lcol = lane & 15;

    const float rA = rn[n0 + nl];
    const float rB = rn[m0 + nl];

    floatx4 acc[4][4];
    #pragma unroll
    for (int i = 0; i < 4; ++i)
        #pragma unroll
        for (int j = 0; j < 4; ++j)
            acc[i][j] = (floatx4)0.f;

    for (int k0 = 0; k0 < C_DIM; k0 += 32) {
        const float* xa = xb + (size_t)(k0 + half * 16) * N_PIX;
        union { unsigned short u[16]; int4 v[2]; } ta, tb;
        #pragma unroll
        for (int j = 0; j < 16; ++j) {
            float va = xa[(size_t)j * N_PIX + n0 + nl];
            float vb = xa[(size_t)j * N_PIX + m0 + nl];
            ta.u[j] = f2bf(va * rA);
            tb.u[j] = f2bf(vb * rB);
        }
        __syncthreads();
        *(int4*)&As[((half * 2 + 0) * 128 + nl) * 8] = ta.v[0];
        *(int4*)&As[((half * 2 + 1) * 128 + nl) * 8] = ta.v[1];
        *(int4*)&Bs[((half * 2 + 0) * 128 + nl) * 8] = tb.v[0];
        *(int4*)&Bs[((half * 2 + 1) * 128 + nl) * 8] = tb.v[1];
        __syncthreads();

        bf16x8 af[4], bfr[4];
        #pragma unroll
        for (int mi = 0; mi < 4; ++mi)
            af[mi] = *(const bf16x8*)&As[(quad * 128 + wr * 64 + mi * 16 + lcol) * 8];
        #pragma unroll
        for (int ni = 0; ni < 4; ++ni)
            bfr[ni] = *(const bf16x8*)&Bs[(quad * 128 + wc * 64 + ni * 16 + lcol) * 8];
        #pragma unroll
        for (int mi = 0; mi < 4; ++mi)
            #pragma unroll
            for (int ni = 0; ni < 4; ++ni)
                acc[mi][ni] = __builtin_amdgcn_mfma_f32_16x16x32_bf16(af[mi], bfr[ni], acc[mi][ni], 0, 0, 0);
    }

    float attv[4];
    #pragma unroll
    for (int ni = 0; ni < 4; ++ni)
        attv[ni] = ab[m0 + wc * 64 + ni * 16 + lcol];

    #pragma unroll
    for (int mi = 0; mi < 4; ++mi) {
        float part[4] = {0.f, 0.f, 0.f, 0.f};
        #pragma unroll
        for (int ni = 0; ni < 4; ++ni) {
            #pragma unroll
            for (int r = 0; r < 4; ++r) {
                float s = fmaxf(acc[mi][ni][r], 0.f);
                part[r] = fmaf(s * s, attv[ni], part[r]);
            }
        }
        #pragma unroll
        for (int r = 0; r < 4; ++r) {
            float v = part[r];
            v += __shfl_xor(v, 1);
            v += __shfl_xor(v, 2);
            v += __shfl_xor(v, 4);
            v += __shfl_xor(v, 8);
            if (lcol == 0)
                atomicAdd(&refine[b * N_PIX + n0 + wr * 64 + mi * 16 + quad * 4 + r], v);
        }
    }
}

__global__ __launch_bounds__(256) void pool_fallback(const float* __restrict__ x,
                                                     const float* __restrict__ refine,
                                                     float* __restrict__ out) {
    const int lane = threadIdx.x & 63;
    const int wave = threadIdx.x >> 6;
    const int gidx = blockIdx.x * 4 + wave;
    const int b = gidx >> 9;
    const float4* xr = (const float4*)(x + (size_t)gidx * N_PIX);
    const float4* rr = (const float4*)(refine + (size_t)b * N_PIX);
    float s = 0.f;
    #pragma unroll
    for (int j = 0; j < 9; ++j) {
        float4 xv = xr[j * 64 + lane];
        float4 rv = rr[j * 64 + lane];
        s += xv.x * rv.x + xv.y * rv.y + xv.z * rv.z + xv.w * rv.w;
    }
    #pragma unroll
    for (int off = 32; off > 0; off >>= 1) s += __shfl_down(s, off);
    if (lane == 0) out[gidx] = s * (1.0f / N_PIX);
}

extern "C" void kernel_launch(void* const* d_in, const int* in_sizes, int n_in,
                              void* d_out, int out_size, void* d_ws, size_t ws_size,
                              hipStream_t stream) {
    const float* x = (const float*)d_in[0];
    const float* w = (const float*)d_in[1];
    float* rn2    = (float*)d_ws;                 // fallback: rnorm
    float* g      = rn2 + NB;                     // fallback: att
    float* refine = g + NB;
    float* accd   = refine + NB;
    float* accs   = accd + NB;
    unsigned short* F = (unsigned short*)(accs + NB);
    float* out    = (float*)d_out;

    const size_t need = (size_t)5 * NB * 4 + (size_t)B_DIM * FB_STRIDE * 2;

    if (ws_size >= need) {
        hipMemsetAsync(accd, 0, (size_t)2 * NB * 4, stream);   // accd + accs
        xcvt_kernel<<<dim3(144, 16), 256, 0, stream>>>(x, w, F, accd, accs);
        finalize_kernel<<<dim3(144), 256, 0, stream>>>(accd, accs, g, rn2, refine);
        refine_kernel<<<dim3(171 * 16), 256, 0, stream>>>(F, g, refine);
        pool_kernel<<<dim3(B_DIM * K8), 256, 0, stream>>>(F, refine, rn2, out);
    } else {
        hipMemsetAsync(refine, 0, (size_t)NB * 4, stream);
        prep_kernel<<<dim3(NB / 64), 256, 0, stream>>>(x, w, rn2, g);
        refine_fallback<<<dim3(18, 18, B_DIM), 256, 0, stream>>>(x, rn2, g, refine);
        pool_fallback<<<dim3(B_DIM * C_DIM / 4), 256, 0, stream>>>(x, refine, out);
    }
}